// Round 13
// baseline (223.326 us; speedup 1.0000x reference)
//
#include <hip/hip_runtime.h>
#include <hip/hip_fp16.h>
#include <cmath>

typedef float f2 __attribute__((ext_vector_type(2)));

// ---------------- Gaussian windows (host-computed, passed by value) ----------
struct GW7  { float g[7];  };
struct GW11 { float g[11]; };
struct GW29 { float g[29]; };

static void make_gauss(int ws, double sigma, float* out) {
    double t[32]; double s = 0.0;
    int c = ws / 2;
    for (int i = 0; i < ws; ++i) { double d = i - c; t[i] = exp(-(d * d) / (2.0 * sigma * sigma)); s += t[i]; }
    for (int i = 0; i < ws; ++i) out[i] = (float)(t[i] / s);
}

// Accumulator slots (each striped x64 doubles):
// 0-4: ssim[level]  5-9: mcs[level]  10: l1  11: clr  12-27: me1[b]  28-43: me3[b]
#define ACC_SLOTS 44
#define ACC_BYTES (ACC_SLOTS * 64 * sizeof(double))

__device__ __forceinline__ float poly5(float x) {
    float r = fmaf(1.556091f, x, -1.894404f);
    r = fmaf(r, x, 1.435936f);
    r = fmaf(r, x, -0.173433f);
    r = fmaf(r, x, 0.07633f);
    r = fmaf(r, x, -0.000519f);
    return r;
}

__device__ __forceinline__ float border7(int p, const GW7& gw) {
    if (p >= 3 && p <= 508) return 1.f;
    float r = 0.f;
    #pragma unroll
    for (int k = 0; k < 7; ++k) { int q = p + 3 - k; if (q >= 0 && q < 512) r += gw.g[k]; }
    return r;
}

#define SSP 49
#define SRP 33
#define CLINE 33           // clr linear row-buffer stride (half2)
#define CROWS 156          // 128 outputs + 28 halo

// ---------------- SSIM tile (shared by fused L0 and levels 1-4) --------------
// Single version (r8 form, 36 VGPR): bounds-checked load, union LDS via
// register snapshot, straight conv loops.
template<bool SRC2>
__device__ __forceinline__ void ssim_tile(
    const float* __restrict__ Aim, const float* __restrict__ Bim,
    const f2* __restrict__ AB, int H, int plane, int ty, int tx,
    const GW11& gw, const GW7& g7, double* __restrict__ acc, int level,
    f2* __restrict__ pooled, int Ho, f2* lds, float* red, int bid)
{
    constexpr int IN = 42;
    f2* s    = lds;                              // load phase: 42 x 49
    f2* r_mu = lds;                              // conv phase: 42 x 33 each
    f2* r_sq = lds + IN * SRP;

    const int tid = threadIdx.x;
    const size_t base = (size_t)plane * H * H;
    const int oy = ty * 32 - 5, ox = tx * 32 - 5;

    for (int i = tid; i < IN * IN; i += 256) {
        int y = i / IN, x = i - y * IN;
        int gy = oy + y, gx = ox + x;
        bool ok = (gy >= 0) && (gy < H) && (gx >= 0) && (gx < H);
        size_t o = base + (size_t)gy * H + gx;
        f2 v = {0.f, 0.f};
        if (ok) {
            if (SRC2) v = AB[o];
            else { v.x = Aim[o]; v.y = Bim[o]; }
        }
        s[y * SSP + x] = v;
    }
    __syncthreads();

    // ---- phase A: snapshot row-conv inputs; pool; L1 (all read s) ----
    f2 v[18];
    const int ry = tid >> 2, rx0 = (tid & 3) * 8;
    if (tid < IN * 4) {
        #pragma unroll
        for (int l = 0; l < 18; ++l) v[l] = s[ry * SSP + rx0 + l];
    }
    if (pooled) {
        int py = tid >> 4, px = tid & 15;
        int a = (5 + 2 * py) * SSP + 5 + 2 * px;
        f2 u = s[a] + s[a + 1] + s[a + SSP] + s[a + SSP + 1];
        pooled[(size_t)plane * Ho * Ho + (size_t)(ty * 16 + py) * Ho + (tx * 16 + px)] = 0.25f * u;
    }
    float l1p = 0.f;
    if (level == 0) {
        #pragma unroll
        for (int jj = 0; jj < 4; ++jj) {
            int p = jj * 256 + tid;
            int py = p >> 5, px = p & 31;
            f2 u = s[(5 + py) * SSP + 5 + px];
            l1p += border7(ty * 32 + py, g7) * border7(tx * 32 + px, g7) * fabsf(u.x - u.y);
        }
    }
    __syncthreads();   // all s reads done; row buffers may overwrite s

    // ---- phase B: packed row conv (straight loops) ----
    if (tid < IN * 4) {
        #pragma unroll
        for (int j = 0; j < 8; ++j) {
            f2 a = {0.f, 0.f};
            #pragma unroll
            for (int k = 0; k < 11; ++k) a = gw.g[k] * v[j + k] + a;
            r_mu[ry * SRP + rx0 + j] = a;
        }
        #pragma unroll
        for (int l = 0; l < 18; ++l) {
            f2 w;
            w.x = fmaf(v[l].x, v[l].x, v[l].y * v[l].y);
            w.y = v[l].x * v[l].y;
            v[l] = w;
        }
        #pragma unroll
        for (int j = 0; j < 8; ++j) {
            f2 a = {0.f, 0.f};
            #pragma unroll
            for (int k = 0; k < 11; ++k) a = gw.g[k] * v[j + k] + a;
            r_sq[ry * SRP + rx0 + j] = a;
        }
    }
    __syncthreads();

    // ---- phase C: packed col conv + pointwise ----
    const int y0 = (tid >> 5) * 4, x = tid & 31;
    float lss = 0.f, lmc = 0.f;
    {
        f2 mu[4], q[4];
        {
            f2 u[14];
            #pragma unroll
            for (int l = 0; l < 14; ++l) u[l] = r_mu[(y0 + l) * SRP + x];
            #pragma unroll
            for (int j = 0; j < 4; ++j) {
                f2 a = {0.f, 0.f};
                #pragma unroll
                for (int k = 0; k < 11; ++k) a = gw.g[k] * u[j + k] + a;
                mu[j] = a;
            }
        }
        {
            f2 u[14];
            #pragma unroll
            for (int l = 0; l < 14; ++l) u[l] = r_sq[(y0 + l) * SRP + x];
            #pragma unroll
            for (int j = 0; j < 4; ++j) {
                f2 a = {0.f, 0.f};
                #pragma unroll
                for (int k = 0; k < 11; ++k) a = gw.g[k] * u[j + k] + a;
                q[j] = a;
            }
        }
        #pragma unroll
        for (int j = 0; j < 4; ++j) {
            float m1 = mu[j].x, m2 = mu[j].y;
            float P = m1 * m2;
            float S = fmaf(m1, m1, m2 * m2);
            float V1 = 2.f * (q[j].y - P) + 58.5225f;
            float V2 = (q[j].x - S) + 58.5225f;
            float num = (2.f * P + 6.5025f) * V1;
            float SC = S + 6.5025f;
            float inv = __builtin_amdgcn_rcpf(SC * V2);
            lss = fmaf(num, inv, lss);
            lmc = fmaf(V1 * SC, inv, lmc);
        }
    }
    #pragma unroll
    for (int o = 32; o > 0; o >>= 1) {
        lss += __shfl_down(lss, o); lmc += __shfl_down(lmc, o); l1p += __shfl_down(l1p, o);
    }
    if ((tid & 63) == 0) {
        int g = tid >> 6;
        red[g * 3] = lss; red[g * 3 + 1] = lmc; red[g * 3 + 2] = l1p;
    }
    __syncthreads();
    if (tid == 0) {
        float a = red[0] + red[3] + red[6] + red[9];
        float m = red[1] + red[4] + red[7] + red[10];
        int stripe = bid & 63;
        atomicAdd(&acc[(0 + level) * 64 + stripe], (double)a);
        atomicAdd(&acc[(5 + level) * 64 + stripe], (double)m);
        if (level == 0) {
            float l1 = red[2] + red[5] + red[8] + red[11];
            atomicAdd(&acc[10 * 64 + stripe], (double)l1);
        }
    }
}

// ---------------- SSIM levels 1-4 (and fallback L0) --------------------------
template<bool SRC2>
__global__ __launch_bounds__(256) void ssim_kernel(
    const float* __restrict__ Aim, const float* __restrict__ Bim, const f2* __restrict__ AB,
    int H, int tpp, int tilesX, GW11 gw, GW7 g7, double* __restrict__ acc, int level,
    f2* __restrict__ pooled, int Ho)
{
    __shared__ f2 lds[2 * 42 * SRP];
    __shared__ float red[12];
    const int bid = blockIdx.x;
    const int plane = bid / tpp;
    const int t = bid - plane * tpp;
    const int ty = t / tilesX, tx = t - ty * tilesX;
    ssim_tile<SRC2>(Aim, Bim, AB, H, plane, ty, tx, gw, g7, acc, level, pooled, Ho, lds, red, bid);
}

// ---------------- CLR quarter-strip (linear 156-row half2 buffer) ------------
// Row conv: straight loops from global (masked loads). Col conv: ROLLING form
// (no u[32] register array -> removes the kernel-wide 64-VGPR live range;
// same LDS read count, each value read once and used 4x).
__device__ __forceinline__ void clr_strip(
    const float* __restrict__ img1, const float* __restrict__ img3,
    int plane, int tx, int q, const GW29& gw, __half2* buf, float* red,
    double* __restrict__ acc, __half2* __restrict__ pbuf, int bid)
{
    const int tid = threadIdx.x;
    const int base_row = q * 128;
    const int b = plane / 3, c = plane - b * 3;
    const float wg = (c == 0) ? 0.299f : (c == 1 ? 0.587f : 0.144f);
    const size_t base = (size_t)plane * (512 * 512);
    const int rrow = tid >> 2, xq = tid & 3;
    const int c0 = tx * 8 + xq * 2 - 4;

    auto rowconv = [&](int rel) {
        __half2* dst = buf + (rel + 14) * CLINE + xq * 8;
        const int lr = base_row + rel;
        if (lr < 0 || lr >= 512) {
            #pragma unroll
            for (int j = 0; j < 8; ++j) dst[j] = __floats2half2_rn(0.f, 0.f);
            return;
        }
        const float4* row1 = (const float4*)(img1 + base + (size_t)lr * 512);
        const float4* row3 = (const float4*)(img3 + base + (size_t)lr * 512);
        float w[40];
        float o1[8];
        #pragma unroll
        for (int k = 0; k < 10; ++k) {
            int cc = c0 + k;
            float4 f = {0.f, 0.f, 0.f, 0.f};
            if (cc >= 0 && cc < 128) f = row1[cc];
            w[4 * k] = f.x; w[4 * k + 1] = f.y; w[4 * k + 2] = f.z; w[4 * k + 3] = f.w;
        }
        #pragma unroll
        for (int j = 0; j < 8; ++j) {
            float a = 0.f;
            #pragma unroll
            for (int k = 0; k < 29; ++k) a = fmaf(gw.g[k], w[2 + j + k], a);
            o1[j] = a;
        }
        #pragma unroll
        for (int k = 0; k < 10; ++k) {
            int cc = c0 + k;
            float4 f = {0.f, 0.f, 0.f, 0.f};
            if (cc >= 0 && cc < 128) f = row3[cc];
            w[4 * k] = f.x; w[4 * k + 1] = f.y; w[4 * k + 2] = f.z; w[4 * k + 3] = f.w;
        }
        #pragma unroll
        for (int j = 0; j < 8; ++j) {
            float a = 0.f;
            #pragma unroll
            for (int k = 0; k < 29; ++k) a = fmaf(gw.g[k], w[2 + j + k], a);
            dst[j] = __floats2half2_rn(o1[j], a);
        }
    };

    rowconv(-14 + rrow);                         // linear rows 0..63
    __syncthreads();

    float p1 = 0.f, p3 = 0.f;
    const int x = tid & 31;
    #pragma unroll
    for (int ck = 0; ck < 2; ++ck) {
        int rel = 50 + 64 * ck + rrow;           // ck0: rows 64..127, ck1: 128..155
        if (rel <= 141) rowconv(rel);
        __syncthreads();
        #pragma unroll
        for (int g = 0; g < 2; ++g) {
            const int y0 = 64 * ck + g * 32 + (tid >> 5) * 4;
            f2 mu[4];
            #pragma unroll
            for (int j = 0; j < 4; ++j) mu[j] = (f2){0.f, 0.f};
            #pragma unroll
            for (int l = 0; l < 32; ++l) {
                float2 tf = __half22float2(buf[(y0 + l) * CLINE + x]);
                f2 val = {tf.x, tf.y};
                #pragma unroll
                for (int j = 0; j < 4; ++j)
                    if (l - j >= 0 && l - j < 29) mu[j] = gw.g[l - j] * val + mu[j];
            }
            #pragma unroll
            for (int j = 0; j < 4; ++j) {
                float p = poly5(mu[j].x);
                p1 += p; p3 += mu[j].y;
                pbuf[base + (size_t)(base_row + y0 + j) * 512 + (tx * 32 + x)] =
                    __floats2half2_rn(p, mu[j].y);
            }
        }
        // no trailing barrier: linear buffer, ck1 writes (rows>=128) are
        // disjoint from ck0 reads (rows<=91)
    }

    p1 *= wg; p3 *= wg;
    #pragma unroll
    for (int o = 32; o > 0; o >>= 1) { p1 += __shfl_down(p1, o); p3 += __shfl_down(p3, o); }
    if ((tid & 63) == 0) { red[(tid >> 6) * 2] = p1; red[(tid >> 6) * 2 + 1] = p3; }
    __syncthreads();
    if (tid == 0) {
        float a1 = red[0] + red[2] + red[4] + red[6];
        float a3 = red[1] + red[3] + red[5] + red[7];
        int stripe = bid & 63;
        atomicAdd(&acc[(12 + b) * 64 + stripe], (double)a1);
        atomicAdd(&acc[(28 + b) * 64 + stripe], (double)a3);
    }
}

// ---------------- Fused L0: clr quarter-strips INTERLEAVED with ssim tiles ---
__global__ __launch_bounds__(256) void fused_l0(
    const float* __restrict__ img1, const float* __restrict__ img2,
    const float* __restrict__ img3,
    GW11 g11, GW7 g7, GW29 g29,
    __half2* __restrict__ pbuf, f2* __restrict__ pooled, double* __restrict__ acc)
{
    __shared__ f2 lds[2 * 42 * SRP];             // 22.2 KB; clr aliases 20.6 KB half2
    __shared__ float red[12];
    const int bid = blockIdx.x;
    const int q5 = bid / 5;

    if (bid - q5 * 5 == 0) {
        // clr block: cid in [0, 3072)
        const int cid = q5;
        __half2* buf = (__half2*)lds;            // CROWS(156) x CLINE(33) half2
        const int plane = cid >> 6, rr = cid & 63;
        const int tx = rr >> 2, q = rr & 3;
        clr_strip(img1, img3, plane, tx, q, g29, buf, red, acc, pbuf, bid);
        return;
    }

    // ssim block: sid in [0, 12288)
    const int sid = bid - q5 - 1;
    const int plane = sid >> 8;
    const int t = sid & 255;
    const int ty = t >> 4, tx = t & 15;
    ssim_tile<false>(img1, img2, nullptr, 512, plane, ty, tx, g11, g7, acc, 0, pooled, 256, lds, red, bid);
}

// ---------------- CLR fallback: full-strip ring (modes 1/2, small ws) --------
#define CRP 33
#define RING 128
template<int MODE>
__global__ __launch_bounds__(256) void clr_conv(
    const float* __restrict__ img1, const float* __restrict__ img3,
    __half2* __restrict__ pbuf, GW29 gw, double* __restrict__ acc)
{
    __shared__ f2 r[RING * CRP];
    __shared__ float red[8];
    __shared__ float sc_sh;

    const int tid = threadIdx.x, bid = blockIdx.x;
    const int plane = bid >> 4, tx = bid & 15;
    const int b = plane / 3, c = plane - b * 3;
    const float wg = (c == 0) ? 0.299f : (c == 1 ? 0.587f : 0.144f);
    const size_t base = (size_t)plane * (512 * 512);

    if (MODE == 2 && tid < 64) {
        double m1 = acc[(12 + b) * 64 + tid];
        double m3 = acc[(28 + b) * 64 + tid];
        #pragma unroll
        for (int o = 32; o > 0; o >>= 1) { m1 += __shfl_down(m1, o); m3 += __shfl_down(m3, o); }
        if (tid == 0) sc_sh = (float)(m1 / m3);
    }

    const int rrow = tid >> 2, xq = tid & 3;
    const int c0 = tx * 8 + xq * 2 - 4;

    auto rowconv = [&](int lr) {
        const int ri = ((lr + RING) & (RING - 1)) * CRP + xq * 8;
        if (lr < 0 || lr >= 512) {
            #pragma unroll
            for (int j = 0; j < 8; ++j) r[ri + j] = (f2){0.f, 0.f};
            return;
        }
        const float4* row1 = (const float4*)(img1 + base + (size_t)lr * 512);
        const float4* row3 = (const float4*)(img3 + base + (size_t)lr * 512);
        float w[40];
        float o1[8];
        #pragma unroll
        for (int k = 0; k < 10; ++k) {
            int cc = c0 + k;
            float4 f = {0.f, 0.f, 0.f, 0.f};
            if (cc >= 0 && cc < 128) f = row1[cc];
            w[4 * k] = f.x; w[4 * k + 1] = f.y; w[4 * k + 2] = f.z; w[4 * k + 3] = f.w;
        }
        #pragma unroll
        for (int j = 0; j < 8; ++j) {
            float a = 0.f;
            #pragma unroll
            for (int k = 0; k < 29; ++k) a = fmaf(gw.g[k], w[2 + j + k], a);
            o1[j] = a;
        }
        #pragma unroll
        for (int k = 0; k < 10; ++k) {
            int cc = c0 + k;
            float4 f = {0.f, 0.f, 0.f, 0.f};
            if (cc >= 0 && cc < 128) f = row3[cc];
            w[4 * k] = f.x; w[4 * k + 1] = f.y; w[4 * k + 2] = f.z; w[4 * k + 3] = f.w;
        }
        #pragma unroll
        for (int j = 0; j < 8; ++j) {
            float a = 0.f;
            #pragma unroll
            for (int k = 0; k < 29; ++k) a = fmaf(gw.g[k], w[2 + j + k], a);
            r[ri + j] = (f2){o1[j], a};
        }
    };

    rowconv(-14 + rrow);
    __syncthreads();

    float p1 = 0.f, p3 = 0.f;
    const int x = tid & 31;
    #pragma unroll 1
    for (int ck = 0; ck < 8; ++ck) {
        {
            int lr = 50 + 64 * ck + rrow;
            if (lr <= 525) rowconv(lr);
        }
        __syncthreads();
        #pragma unroll
        for (int g = 0; g < 2; ++g) {
            const int y0 = 64 * ck + g * 32 + (tid >> 5) * 4;
            f2 mu[4];
            #pragma unroll
            for (int j = 0; j < 4; ++j) mu[j] = (f2){0.f, 0.f};
            #pragma unroll
            for (int l = 0; l < 32; ++l) {
                f2 val = r[(((y0 - 14 + l) + RING) & (RING - 1)) * CRP + x];
                #pragma unroll
                for (int j = 0; j < 4; ++j)
                    if (l - j >= 0 && l - j < 29) mu[j] = gw.g[l - j] * val + mu[j];
            }
            #pragma unroll
            for (int j = 0; j < 4; ++j) {
                float p = poly5(mu[j].x);
                if (MODE == 2) {
                    p1 += fabsf(p - mu[j].y * sc_sh);
                } else {
                    p1 += p; p3 += mu[j].y;
                }
            }
        }
        if (ck < 7) __syncthreads();
    }

    if (MODE != 2) { p1 *= wg; p3 *= wg; }
    #pragma unroll
    for (int o = 32; o > 0; o >>= 1) { p1 += __shfl_down(p1, o); p3 += __shfl_down(p3, o); }
    if ((tid & 63) == 0) { red[(tid >> 6) * 2] = p1; red[(tid >> 6) * 2 + 1] = p3; }
    __syncthreads();
    if (tid == 0) {
        float a1 = red[0] + red[2] + red[4] + red[6];
        int stripe = bid & 63;
        if (MODE == 2) {
            atomicAdd(&acc[11 * 64 + stripe], (double)a1);
        } else {
            float a3 = red[1] + red[3] + red[5] + red[7];
            atomicAdd(&acc[(12 + b) * 64 + stripe], (double)a1);
            atomicAdd(&acc[(28 + b) * 64 + stripe], (double)a3);
        }
    }
}

// ---------------- CLR finish: |p - mu3*sc| over stored half2 -----------------
__global__ __launch_bounds__(256) void clr_fin(
    const __half2* __restrict__ pbuf, double* __restrict__ acc)
{
    __shared__ float red[4];
    __shared__ float sc_sh;
    const int tid = threadIdx.x, bid = blockIdx.x;
    const int b = bid / 192, sub = bid - b * 192;
    if (tid < 64) {
        double m1 = acc[(12 + b) * 64 + tid];
        double m3 = acc[(28 + b) * 64 + tid];
        #pragma unroll
        for (int o = 32; o > 0; o >>= 1) { m1 += __shfl_down(m1, o); m3 += __shfl_down(m3, o); }
        if (tid == 0) sc_sh = (float)(m1 / m3);
    }
    __syncthreads();
    const float sc = sc_sh;
    const size_t bo = (size_t)b * 786432 + (size_t)sub * 4096;
    float s = 0.f;
    #pragma unroll
    for (int it = 0; it < 8; ++it) {
        size_t i = bo + it * 512 + tid * 2;
        float2 a = __half22float2(pbuf[i]);
        float2 c = __half22float2(pbuf[i + 1]);
        s += fabsf(a.x - a.y * sc) + fabsf(c.x - c.y * sc);
    }
    #pragma unroll
    for (int o = 32; o > 0; o >>= 1) s += __shfl_down(s, o);
    if ((tid & 63) == 0) red[tid >> 6] = s;
    __syncthreads();
    if (tid == 0)
        atomicAdd(&acc[11 * 64 + (bid & 63)], (double)(red[0] + red[1] + red[2] + red[3]));
}

// ---------------- Finalize: combine everything into the scalar ---------------
__global__ void finalize_kernel(const double* __restrict__ acc, float* __restrict__ out)
{
    __shared__ double sums[ACC_SLOTS];
    int t = threadIdx.x;
    if (t < ACC_SLOTS) {
        double s = 0.0;
        for (int i = 0; i < 64; ++i) s += acc[t * 64 + i];
        sums[t] = s;
    }
    __syncthreads();
    if (t == 0) {
        const double w[5] = {0.0448, 0.2856, 0.3001, 0.2363, 0.1333};
        double value = 1.0;
        for (int l = 0; l < 5; ++l) {
            double dim = (double)(512 >> l);
            double cnt = 48.0 * dim * dim;
            double mval = (l < 4) ? (sums[5 + l] / cnt) : (sums[l] / cnt);
            value *= pow(mval, w[l]);
        }
        double n0 = 48.0 * 512.0 * 512.0;
        double l1v = sums[10] / n0;
        double clrv = sums[11] / n0;
        out[0] = (float)(0.4 * (1.0 - value) + 0.4 * l1v + 0.2 * clrv);
    }
}

// ---------------- Launch ------------------------------------------------------
extern "C" void kernel_launch(void* const* d_in, const int* in_sizes, int n_in,
                              void* d_out, int out_size, void* d_ws, size_t ws_size,
                              hipStream_t stream)
{
    (void)in_sizes; (void)n_in; (void)out_size;
    const float* img1 = (const float*)d_in[0];
    const float* img2 = (const float*)d_in[1];
    const float* img3 = (const float*)d_in[2];
    float* out = (float*)d_out;
    double* acc = (double*)d_ws;

    GW11 g11; make_gauss(11, 1.5, g11.g);
    GW7  g7;  make_gauss(7, 1.1, g7.g);
    GW29 g29; make_gauss(29, 29.0 / 6.0, g29.g);

    hipMemsetAsync(d_ws, 0, ACC_BYTES, stream);

    // Interleaved (A,B) float2 pyramid for levels 1..4
    f2* pyr = (f2*)((char*)d_ws + 32768);
    size_t offs[4];
    offs[0] = 0;
    offs[1] = offs[0] + (size_t)48 * 256 * 256;
    offs[2] = offs[1] + (size_t)48 * 128 * 128;
    offs[3] = offs[2] + (size_t)48 * 64 * 64;
    const size_t PYRF2 = offs[3] + (size_t)48 * 32 * 32;

    const size_t poff = 32768 + PYRF2 * sizeof(f2);
    const size_t PBYTES = (size_t)48 * 512 * 512 * sizeof(__half2);
    __half2* pbuf = (__half2*)((char*)d_ws + poff);
    const bool bigws = (ws_size >= poff + PBYTES);

    if (bigws) {
        fused_l0<<<15360, 256, 0, stream>>>(img1, img2, img3, g11, g7, g29,
                                            pbuf, pyr + offs[0], acc);
    } else {
        ssim_kernel<false><<<12288, 256, 0, stream>>>(
            img1, img2, nullptr, 512, 256, 16, g11, g7, acc, 0, pyr + offs[0], 256);
        clr_conv<1><<<768, 256, 0, stream>>>(img1, img3, pbuf, g29, acc);
    }

    // MS-SSIM levels 1..4 on the pyramid
    const f2* cur = pyr + offs[0];
    int H = 256;
    for (int l = 1; l < 5; ++l) {
        int tilesX = H / 32; int tpp = tilesX * tilesX;
        f2* pooled = (l < 4) ? (pyr + offs[l]) : nullptr;
        int Ho = H / 2;
        ssim_kernel<true><<<48 * tpp, 256, 0, stream>>>(
            nullptr, nullptr, cur, H, tpp, tilesX, g11, g7, acc, l, pooled, Ho);
        cur = pooled; H = Ho;
    }

    if (bigws) {
        clr_fin<<<3072, 256, 0, stream>>>(pbuf, acc);
    } else {
        clr_conv<2><<<768, 256, 0, stream>>>(img1, img3, pbuf, g29, acc);
    }

    finalize_kernel<<<1, 64, 0, stream>>>(acc, out);
}

// Round 14
// 208.632 us; speedup vs baseline: 1.0704x; 1.0704x over previous
//
#include <hip/hip_runtime.h>
#include <hip/hip_fp16.h>
#include <cmath>

typedef float f2 __attribute__((ext_vector_type(2)));

// ---------------- Gaussian windows (host-computed, passed by value) ----------
struct GW7  { float g[7];  };
struct GW11 { float g[11]; };
struct GW29 { float g[29]; };

static void make_gauss(int ws, double sigma, float* out) {
    double t[32]; double s = 0.0;
    int c = ws / 2;
    for (int i = 0; i < ws; ++i) { double d = i - c; t[i] = exp(-(d * d) / (2.0 * sigma * sigma)); s += t[i]; }
    for (int i = 0; i < ws; ++i) out[i] = (float)(t[i] / s);
}

// Accumulator slots (each striped x64 doubles):
// 0-4: ssim[level]  5-9: mcs[level]  10: l1  11: clr  12-27: me1[b]  28-43: me3[b]
#define ACC_SLOTS 44
#define ACC_BYTES (ACC_SLOTS * 64 * sizeof(double))

__device__ __forceinline__ float poly5(float x) {
    float r = fmaf(1.556091f, x, -1.894404f);
    r = fmaf(r, x, 1.435936f);
    r = fmaf(r, x, -0.173433f);
    r = fmaf(r, x, 0.07633f);
    r = fmaf(r, x, -0.000519f);
    return r;
}

__device__ __forceinline__ float border7(int p, const GW7& gw) {
    if (p >= 3 && p <= 508) return 1.f;
    float r = 0.f;
    #pragma unroll
    for (int k = 0; k < 7; ++k) { int q = p + 3 - k; if (q >= 0 && q < 512) r += gw.g[k]; }
    return r;
}

#define SSP 49
#define SRP 33
#define CLINE 33           // clr ring row stride (half2)

// ---------------- SSIM tile: single row-buffer, 4-phase ----------------------
// LDS = 42x49 f2 (16.5 KB); ONE 42x33 row buffer aliased into it. Input
// snapshot v[18] (row-conv threads) carries data across phases. Col convs in
// rolling form (same FMA count, small live set).
template<bool SRC2, bool INTERIOR>
__device__ __forceinline__ void ssim_tile(
    const float* __restrict__ Aim, const float* __restrict__ Bim,
    const f2* __restrict__ AB, int H, int plane, int ty, int tx,
    const GW11& gw, const GW7& g7, double* __restrict__ acc, int level,
    f2* __restrict__ pooled, int Ho, f2* lds, float* red, int bid)
{
    constexpr int IN = 42;
    f2* s = lds;                                 // load phase: 42 x 49
    f2* r = lds;                                 // conv phases: 42 x 33 (aliased)

    const int tid = threadIdx.x;
    const size_t base = (size_t)plane * H * H;
    const int oy = ty * 32 - 5, ox = tx * 32 - 5;

    // ---- load 42x42 (one magic-div, incremental y/x) ----
    {
        int y = tid / 42;
        int x = tid - y * 42;
        #pragma unroll
        for (int it = 0; it < 7; ++it) {
            if (it < 6 || tid < 228) {
                f2 v;
                if (INTERIOR) {
                    size_t o = base + (size_t)(oy + y) * H + (ox + x);
                    if (SRC2) v = AB[o];
                    else { v.x = Aim[o]; v.y = Bim[o]; }
                } else {
                    int gy = oy + y, gx = ox + x;
                    bool ok = (gy >= 0) && (gy < H) && (gx >= 0) && (gx < H);
                    size_t o = base + (size_t)gy * H + gx;
                    v = (f2){0.f, 0.f};
                    if (ok) { if (SRC2) v = AB[o]; else { v.x = Aim[o]; v.y = Bim[o]; } }
                }
                s[y * SSP + x] = v;
            }
            y += 6; x += 4; if (x >= 42) { x -= 42; ++y; }
        }
    }
    __syncthreads();

    // ---- phase A: snapshot row-conv inputs; pool; L1 (all read s) ----
    f2 v[18];
    const int ry = tid >> 2, rx0 = (tid & 3) * 8;
    if (tid < IN * 4) {
        #pragma unroll
        for (int l = 0; l < 18; ++l) v[l] = s[ry * SSP + rx0 + l];
    }
    if (pooled) {
        int py = tid >> 4, px = tid & 15;
        int a = (5 + 2 * py) * SSP + 5 + 2 * px;
        f2 u = s[a] + s[a + 1] + s[a + SSP] + s[a + SSP + 1];
        pooled[(size_t)plane * Ho * Ho + (size_t)(ty * 16 + py) * Ho + (tx * 16 + px)] = 0.25f * u;
    }
    float l1p = 0.f;
    if (level == 0) {
        #pragma unroll
        for (int jj = 0; jj < 4; ++jj) {
            int p = jj * 256 + tid;
            int py = p >> 5, px = p & 31;
            f2 u = s[(5 + py) * SSP + 5 + px];
            float d = fabsf(u.x - u.y);
            if (INTERIOR) l1p += d;
            else l1p += border7(ty * 32 + py, g7) * border7(tx * 32 + px, g7) * d;
        }
    }
    __syncthreads();   // all s reads done; row buffer may overwrite s

    // ---- B1: row conv of (A,B) ----
    if (tid < IN * 4) {
        #pragma unroll
        for (int j = 0; j < 8; ++j) {
            f2 a = {0.f, 0.f};
            #pragma unroll
            for (int k = 0; k < 11; ++k) a = gw.g[k] * v[j + k] + a;
            r[ry * SRP + rx0 + j] = a;
        }
    }
    __syncthreads();

    // ---- C1: col conv mu (rolling; result stays in registers) ----
    const int y0 = (tid >> 5) * 4, x = tid & 31;
    f2 mu[4];
    #pragma unroll
    for (int j = 0; j < 4; ++j) mu[j] = (f2){0.f, 0.f};
    #pragma unroll
    for (int l = 0; l < 14; ++l) {
        f2 val = r[(y0 + l) * SRP + x];
        #pragma unroll
        for (int j = 0; j < 4; ++j)
            if (l - j >= 0 && l - j < 11) mu[j] = gw.g[l - j] * val + mu[j];
    }
    __syncthreads();

    // ---- B2: squares in place, row conv of (A^2+B^2, A*B) ----
    if (tid < IN * 4) {
        #pragma unroll
        for (int l = 0; l < 18; ++l) {
            f2 w;
            w.x = fmaf(v[l].x, v[l].x, v[l].y * v[l].y);
            w.y = v[l].x * v[l].y;
            v[l] = w;
        }
        #pragma unroll
        for (int j = 0; j < 8; ++j) {
            f2 a = {0.f, 0.f};
            #pragma unroll
            for (int k = 0; k < 11; ++k) a = gw.g[k] * v[j + k] + a;
            r[ry * SRP + rx0 + j] = a;
        }
    }
    __syncthreads();

    // ---- C2: col conv q (rolling) + pointwise ----
    float lss = 0.f, lmc = 0.f;
    {
        f2 q[4];
        #pragma unroll
        for (int j = 0; j < 4; ++j) q[j] = (f2){0.f, 0.f};
        #pragma unroll
        for (int l = 0; l < 14; ++l) {
            f2 val = r[(y0 + l) * SRP + x];
            #pragma unroll
            for (int j = 0; j < 4; ++j)
                if (l - j >= 0 && l - j < 11) q[j] = gw.g[l - j] * val + q[j];
        }
        #pragma unroll
        for (int j = 0; j < 4; ++j) {
            float m1 = mu[j].x, m2 = mu[j].y;
            float P = m1 * m2;
            float S = fmaf(m1, m1, m2 * m2);
            float V1 = 2.f * (q[j].y - P) + 58.5225f;
            float V2 = (q[j].x - S) + 58.5225f;
            float num = (2.f * P + 6.5025f) * V1;
            float SC = S + 6.5025f;
            float inv = __builtin_amdgcn_rcpf(SC * V2);
            lss = fmaf(num, inv, lss);
            lmc = fmaf(V1 * SC, inv, lmc);
        }
    }
    #pragma unroll
    for (int o = 32; o > 0; o >>= 1) {
        lss += __shfl_down(lss, o); lmc += __shfl_down(lmc, o); l1p += __shfl_down(l1p, o);
    }
    if ((tid & 63) == 0) {
        int g = tid >> 6;
        red[g * 3] = lss; red[g * 3 + 1] = lmc; red[g * 3 + 2] = l1p;
    }
    __syncthreads();
    if (tid == 0) {
        float a = red[0] + red[3] + red[6] + red[9];
        float m = red[1] + red[4] + red[7] + red[10];
        int stripe = bid & 63;
        atomicAdd(&acc[(0 + level) * 64 + stripe], (double)a);
        atomicAdd(&acc[(5 + level) * 64 + stripe], (double)m);
        if (level == 0) {
            float l1 = red[2] + red[5] + red[8] + red[11];
            atomicAdd(&acc[10 * 64 + stripe], (double)l1);
        }
    }
}

// ---------------- SSIM levels 1-4 (and fallback L0) --------------------------
template<bool SRC2>
__global__ __launch_bounds__(256) void ssim_kernel(
    const float* __restrict__ Aim, const float* __restrict__ Bim, const f2* __restrict__ AB,
    int H, int tpp, int tilesX, GW11 gw, GW7 g7, double* __restrict__ acc, int level,
    f2* __restrict__ pooled, int Ho)
{
    __shared__ f2 lds[42 * SSP];
    __shared__ float red[12];
    const int bid = blockIdx.x;
    const int plane = bid / tpp;
    const int t = bid - plane * tpp;
    const int ty = t / tilesX, tx = t - ty * tilesX;
    const bool interior = (ty > 0) && (ty < tilesX - 1) && (tx > 0) && (tx < tilesX - 1);
    if (interior)
        ssim_tile<SRC2, true >(Aim, Bim, AB, H, plane, ty, tx, gw, g7, acc, level, pooled, Ho, lds, red, bid);
    else
        ssim_tile<SRC2, false>(Aim, Bim, AB, H, plane, ty, tx, gw, g7, acc, level, pooled, Ho, lds, red, bid);
}

// ---------------- CLR quarter-strip (128-slot half2 ring, 16.9 KB) -----------
// Row conv: r12 straight form from global. Col conv: rolling (small live set).
template<bool CCLEAN>
__device__ __forceinline__ void clr_strip(
    const float* __restrict__ img1, const float* __restrict__ img3,
    int plane, int tx, int q, const GW29& gw, __half2* buf, float* red,
    double* __restrict__ acc, __half2* __restrict__ pbuf, int bid)
{
    const int tid = threadIdx.x;
    const int base_row = q * 128;                // multiple of 128 -> slot = rel & 127
    const int b = plane / 3, c = plane - b * 3;
    const float wg = (c == 0) ? 0.299f : (c == 1 ? 0.587f : 0.144f);
    const size_t base = (size_t)plane * (512 * 512);
    const int rrow = tid >> 2, xq = tid & 3;
    const int c0 = tx * 8 + xq * 2 - 4;

    auto rowconv = [&](int rel) {
        const int slot = (rel + 128) & 127;
        __half2* dst = buf + slot * CLINE + xq * 8;
        const int lr = base_row + rel;
        if (lr < 0 || lr >= 512) {
            #pragma unroll
            for (int j = 0; j < 8; ++j) dst[j] = __floats2half2_rn(0.f, 0.f);
            return;
        }
        const float4* row1 = (const float4*)(img1 + base + (size_t)lr * 512);
        const float4* row3 = (const float4*)(img3 + base + (size_t)lr * 512);
        float w[40];
        float o1[8];
        #pragma unroll
        for (int k = 0; k < 10; ++k) {
            float4 f;
            if (CCLEAN) f = row1[c0 + k];
            else {
                int cc = c0 + k;
                f = (float4){0.f, 0.f, 0.f, 0.f};
                if (cc >= 0 && cc < 128) f = row1[cc];
            }
            w[4 * k] = f.x; w[4 * k + 1] = f.y; w[4 * k + 2] = f.z; w[4 * k + 3] = f.w;
        }
        #pragma unroll
        for (int j = 0; j < 8; ++j) {
            float a = 0.f;
            #pragma unroll
            for (int k = 0; k < 29; ++k) a = fmaf(gw.g[k], w[2 + j + k], a);
            o1[j] = a;
        }
        #pragma unroll
        for (int k = 0; k < 10; ++k) {
            float4 f;
            if (CCLEAN) f = row3[c0 + k];
            else {
                int cc = c0 + k;
                f = (float4){0.f, 0.f, 0.f, 0.f};
                if (cc >= 0 && cc < 128) f = row3[cc];
            }
            w[4 * k] = f.x; w[4 * k + 1] = f.y; w[4 * k + 2] = f.z; w[4 * k + 3] = f.w;
        }
        #pragma unroll
        for (int j = 0; j < 8; ++j) {
            float a = 0.f;
            #pragma unroll
            for (int k = 0; k < 29; ++k) a = fmaf(gw.g[k], w[2 + j + k], a);
            dst[j] = __floats2half2_rn(o1[j], a);
        }
    };

    rowconv(-14 + rrow);                         // rels -14..49
    __syncthreads();

    float p1 = 0.f, p3 = 0.f;
    const int x = tid & 31;
    #pragma unroll
    for (int ck = 0; ck < 2; ++ck) {
        int rel = 50 + 64 * ck + rrow;           // ck0: 50..113, ck1: 114..141
        if (rel <= 141) rowconv(rel);
        __syncthreads();
        #pragma unroll
        for (int g = 0; g < 2; ++g) {
            const int y0 = 64 * ck + g * 32 + (tid >> 5) * 4;
            f2 mu[4];
            #pragma unroll
            for (int j = 0; j < 4; ++j) mu[j] = (f2){0.f, 0.f};
            #pragma unroll
            for (int l = 0; l < 32; ++l) {
                const int slot = (y0 - 14 + l + 128) & 127;
                float2 tf = __half22float2(buf[slot * CLINE + x]);
                f2 val = {tf.x, tf.y};
                #pragma unroll
                for (int j = 0; j < 4; ++j)
                    if (l - j >= 0 && l - j < 29) mu[j] = gw.g[l - j] * val + mu[j];
            }
            #pragma unroll
            for (int j = 0; j < 4; ++j) {
                float p = poly5(mu[j].x);
                p1 += p; p3 += mu[j].y;
                pbuf[base + (size_t)(base_row + y0 + j) * 512 + (tx * 32 + x)] =
                    __floats2half2_rn(p, mu[j].y);
            }
        }
        if (ck == 0) __syncthreads();            // ring slots reused by ck1 writes
    }

    p1 *= wg; p3 *= wg;
    #pragma unroll
    for (int o = 32; o > 0; o >>= 1) { p1 += __shfl_down(p1, o); p3 += __shfl_down(p3, o); }
    if ((tid & 63) == 0) { red[(tid >> 6) * 2] = p1; red[(tid >> 6) * 2 + 1] = p3; }
    __syncthreads();
    if (tid == 0) {
        float a1 = red[0] + red[2] + red[4] + red[6];
        float a3 = red[1] + red[3] + red[5] + red[7];
        int stripe = bid & 63;
        atomicAdd(&acc[(12 + b) * 64 + stripe], (double)a1);
        atomicAdd(&acc[(28 + b) * 64 + stripe], (double)a3);
    }
}

// ---------------- Fused L0: clr quarter-strips INTERLEAVED with ssim tiles ---
__global__ __launch_bounds__(256) void fused_l0(
    const float* __restrict__ img1, const float* __restrict__ img2,
    const float* __restrict__ img3,
    GW11 g11, GW7 g7, GW29 g29,
    __half2* __restrict__ pbuf, f2* __restrict__ pooled, double* __restrict__ acc)
{
    __shared__ f2 lds[2112];                     // 16.9 KB: ssim 42x49 f2 / clr 128x33 half2
    __shared__ float red[12];
    const int bid = blockIdx.x;
    const int q5 = bid / 5;

    if (bid - q5 * 5 == 0) {
        // clr block: cid in [0, 3072)
        const int cid = q5;
        __half2* buf = (__half2*)lds;
        const int plane = cid >> 6, rr = cid & 63;
        const int tx = rr >> 2, q = rr & 3;
        if (tx >= 1 && tx <= 14)
            clr_strip<true >(img1, img3, plane, tx, q, g29, buf, red, acc, pbuf, bid);
        else
            clr_strip<false>(img1, img3, plane, tx, q, g29, buf, red, acc, pbuf, bid);
        return;
    }

    // ssim block: sid in [0, 12288)
    const int sid = bid - q5 - 1;
    const int plane = sid >> 8;
    const int t = sid & 255;
    const int ty = t >> 4, tx = t & 15;
    const bool interior = (ty >= 1) && (ty <= 14) && (tx >= 1) && (tx <= 14);
    if (interior)
        ssim_tile<false, true >(img1, img2, nullptr, 512, plane, ty, tx, g11, g7, acc, 0, pooled, 256, lds, red, bid);
    else
        ssim_tile<false, false>(img1, img2, nullptr, 512, plane, ty, tx, g11, g7, acc, 0, pooled, 256, lds, red, bid);
}

// ---------------- CLR fallback: full-strip ring (modes 1/2, small ws) --------
#define CRP 33
#define RING 128
template<int MODE>
__global__ __launch_bounds__(256) void clr_conv(
    const float* __restrict__ img1, const float* __restrict__ img3,
    __half2* __restrict__ pbuf, GW29 gw, double* __restrict__ acc)
{
    __shared__ f2 r[RING * CRP];
    __shared__ float red[8];
    __shared__ float sc_sh;

    const int tid = threadIdx.x, bid = blockIdx.x;
    const int plane = bid >> 4, tx = bid & 15;
    const int b = plane / 3, c = plane - b * 3;
    const float wg = (c == 0) ? 0.299f : (c == 1 ? 0.587f : 0.144f);
    const size_t base = (size_t)plane * (512 * 512);

    if (MODE == 2 && tid < 64) {
        double m1 = acc[(12 + b) * 64 + tid];
        double m3 = acc[(28 + b) * 64 + tid];
        #pragma unroll
        for (int o = 32; o > 0; o >>= 1) { m1 += __shfl_down(m1, o); m3 += __shfl_down(m3, o); }
        if (tid == 0) sc_sh = (float)(m1 / m3);
    }

    const int rrow = tid >> 2, xq = tid & 3;
    const int c0 = tx * 8 + xq * 2 - 4;

    auto rowconv = [&](int lr) {
        const int ri = ((lr + RING) & (RING - 1)) * CRP + xq * 8;
        if (lr < 0 || lr >= 512) {
            #pragma unroll
            for (int j = 0; j < 8; ++j) r[ri + j] = (f2){0.f, 0.f};
            return;
        }
        const float4* row1 = (const float4*)(img1 + base + (size_t)lr * 512);
        const float4* row3 = (const float4*)(img3 + base + (size_t)lr * 512);
        float w[40];
        float o1[8];
        #pragma unroll
        for (int k = 0; k < 10; ++k) {
            int cc = c0 + k;
            float4 f = {0.f, 0.f, 0.f, 0.f};
            if (cc >= 0 && cc < 128) f = row1[cc];
            w[4 * k] = f.x; w[4 * k + 1] = f.y; w[4 * k + 2] = f.z; w[4 * k + 3] = f.w;
        }
        #pragma unroll
        for (int j = 0; j < 8; ++j) {
            float a = 0.f;
            #pragma unroll
            for (int k = 0; k < 29; ++k) a = fmaf(gw.g[k], w[2 + j + k], a);
            o1[j] = a;
        }
        #pragma unroll
        for (int k = 0; k < 10; ++k) {
            int cc = c0 + k;
            float4 f = {0.f, 0.f, 0.f, 0.f};
            if (cc >= 0 && cc < 128) f = row3[cc];
            w[4 * k] = f.x; w[4 * k + 1] = f.y; w[4 * k + 2] = f.z; w[4 * k + 3] = f.w;
        }
        #pragma unroll
        for (int j = 0; j < 8; ++j) {
            float a = 0.f;
            #pragma unroll
            for (int k = 0; k < 29; ++k) a = fmaf(gw.g[k], w[2 + j + k], a);
            r[ri + j] = (f2){o1[j], a};
        }
    };

    rowconv(-14 + rrow);
    __syncthreads();

    float p1 = 0.f, p3 = 0.f;
    const int x = tid & 31;
    #pragma unroll 1
    for (int ck = 0; ck < 8; ++ck) {
        {
            int lr = 50 + 64 * ck + rrow;
            if (lr <= 525) rowconv(lr);
        }
        __syncthreads();
        #pragma unroll
        for (int g = 0; g < 2; ++g) {
            const int y0 = 64 * ck + g * 32 + (tid >> 5) * 4;
            f2 mu[4];
            #pragma unroll
            for (int j = 0; j < 4; ++j) mu[j] = (f2){0.f, 0.f};
            #pragma unroll
            for (int l = 0; l < 32; ++l) {
                f2 val = r[(((y0 - 14 + l) + RING) & (RING - 1)) * CRP + x];
                #pragma unroll
                for (int j = 0; j < 4; ++j)
                    if (l - j >= 0 && l - j < 29) mu[j] = gw.g[l - j] * val + mu[j];
            }
            #pragma unroll
            for (int j = 0; j < 4; ++j) {
                float p = poly5(mu[j].x);
                if (MODE == 2) {
                    p1 += fabsf(p - mu[j].y * sc_sh);
                } else {
                    p1 += p; p3 += mu[j].y;
                }
            }
        }
        if (ck < 7) __syncthreads();
    }

    if (MODE != 2) { p1 *= wg; p3 *= wg; }
    #pragma unroll
    for (int o = 32; o > 0; o >>= 1) { p1 += __shfl_down(p1, o); p3 += __shfl_down(p3, o); }
    if ((tid & 63) == 0) { red[(tid >> 6) * 2] = p1; red[(tid >> 6) * 2 + 1] = p3; }
    __syncthreads();
    if (tid == 0) {
        float a1 = red[0] + red[2] + red[4] + red[6];
        int stripe = bid & 63;
        if (MODE == 2) {
            atomicAdd(&acc[11 * 64 + stripe], (double)a1);
        } else {
            float a3 = red[1] + red[3] + red[5] + red[7];
            atomicAdd(&acc[(12 + b) * 64 + stripe], (double)a1);
            atomicAdd(&acc[(28 + b) * 64 + stripe], (double)a3);
        }
    }
}

// ---------------- CLR finish: |p - mu3*sc| over stored half2 -----------------
__global__ __launch_bounds__(256) void clr_fin(
    const __half2* __restrict__ pbuf, double* __restrict__ acc)
{
    __shared__ float red[4];
    __shared__ float sc_sh;
    const int tid = threadIdx.x, bid = blockIdx.x;
    const int b = bid / 192, sub = bid - b * 192;
    if (tid < 64) {
        double m1 = acc[(12 + b) * 64 + tid];
        double m3 = acc[(28 + b) * 64 + tid];
        #pragma unroll
        for (int o = 32; o > 0; o >>= 1) { m1 += __shfl_down(m1, o); m3 += __shfl_down(m3, o); }
        if (tid == 0) sc_sh = (float)(m1 / m3);
    }
    __syncthreads();
    const float sc = sc_sh;
    const size_t bo = (size_t)b * 786432 + (size_t)sub * 4096;
    float s = 0.f;
    #pragma unroll
    for (int it = 0; it < 8; ++it) {
        size_t i = bo + it * 512 + tid * 2;
        float2 a = __half22float2(pbuf[i]);
        float2 c = __half22float2(pbuf[i + 1]);
        s += fabsf(a.x - a.y * sc) + fabsf(c.x - c.y * sc);
    }
    #pragma unroll
    for (int o = 32; o > 0; o >>= 1) s += __shfl_down(s, o);
    if ((tid & 63) == 0) red[tid >> 6] = s;
    __syncthreads();
    if (tid == 0)
        atomicAdd(&acc[11 * 64 + (bid & 63)], (double)(red[0] + red[1] + red[2] + red[3]));
}

// ---------------- Finalize: combine everything into the scalar ---------------
__global__ void finalize_kernel(const double* __restrict__ acc, float* __restrict__ out)
{
    __shared__ double sums[ACC_SLOTS];
    int t = threadIdx.x;
    if (t < ACC_SLOTS) {
        double s = 0.0;
        for (int i = 0; i < 64; ++i) s += acc[t * 64 + i];
        sums[t] = s;
    }
    __syncthreads();
    if (t == 0) {
        const double w[5] = {0.0448, 0.2856, 0.3001, 0.2363, 0.1333};
        double value = 1.0;
        for (int l = 0; l < 5; ++l) {
            double dim = (double)(512 >> l);
            double cnt = 48.0 * dim * dim;
            double mval = (l < 4) ? (sums[5 + l] / cnt) : (sums[l] / cnt);
            value *= pow(mval, w[l]);
        }
        double n0 = 48.0 * 512.0 * 512.0;
        double l1v = sums[10] / n0;
        double clrv = sums[11] / n0;
        out[0] = (float)(0.4 * (1.0 - value) + 0.4 * l1v + 0.2 * clrv);
    }
}

// ---------------- Launch ------------------------------------------------------
extern "C" void kernel_launch(void* const* d_in, const int* in_sizes, int n_in,
                              void* d_out, int out_size, void* d_ws, size_t ws_size,
                              hipStream_t stream)
{
    (void)in_sizes; (void)n_in; (void)out_size;
    const float* img1 = (const float*)d_in[0];
    const float* img2 = (const float*)d_in[1];
    const float* img3 = (const float*)d_in[2];
    float* out = (float*)d_out;
    double* acc = (double*)d_ws;

    GW11 g11; make_gauss(11, 1.5, g11.g);
    GW7  g7;  make_gauss(7, 1.1, g7.g);
    GW29 g29; make_gauss(29, 29.0 / 6.0, g29.g);

    hipMemsetAsync(d_ws, 0, ACC_BYTES, stream);

    // Interleaved (A,B) float2 pyramid for levels 1..4
    f2* pyr = (f2*)((char*)d_ws + 32768);
    size_t offs[4];
    offs[0] = 0;
    offs[1] = offs[0] + (size_t)48 * 256 * 256;
    offs[2] = offs[1] + (size_t)48 * 128 * 128;
    offs[3] = offs[2] + (size_t)48 * 64 * 64;
    const size_t PYRF2 = offs[3] + (size_t)48 * 32 * 32;

    const size_t poff = 32768 + PYRF2 * sizeof(f2);
    const size_t PBYTES = (size_t)48 * 512 * 512 * sizeof(__half2);
    __half2* pbuf = (__half2*)((char*)d_ws + poff);
    const bool bigws = (ws_size >= poff + PBYTES);

    if (bigws) {
        fused_l0<<<15360, 256, 0, stream>>>(img1, img2, img3, g11, g7, g29,
                                            pbuf, pyr + offs[0], acc);
    } else {
        ssim_kernel<false><<<12288, 256, 0, stream>>>(
            img1, img2, nullptr, 512, 256, 16, g11, g7, acc, 0, pyr + offs[0], 256);
        clr_conv<1><<<768, 256, 0, stream>>>(img1, img3, pbuf, g29, acc);
    }

    // MS-SSIM levels 1..4 on the pyramid
    const f2* cur = pyr + offs[0];
    int H = 256;
    for (int l = 1; l < 5; ++l) {
        int tilesX = H / 32; int tpp = tilesX * tilesX;
        f2* pooled = (l < 4) ? (pyr + offs[l]) : nullptr;
        int Ho = H / 2;
        ssim_kernel<true><<<48 * tpp, 256, 0, stream>>>(
            nullptr, nullptr, cur, H, tpp, tilesX, g11, g7, acc, l, pooled, Ho);
        cur = pooled; H = Ho;
    }

    if (bigws) {
        clr_fin<<<3072, 256, 0, stream>>>(pbuf, acc);
    } else {
        clr_conv<2><<<768, 256, 0, stream>>>(img1, img3, pbuf, g29, acc);
    }

    finalize_kernel<<<1, 64, 0, stream>>>(acc, out);
}

// Round 15
// 208.570 us; speedup vs baseline: 1.0707x; 1.0003x over previous
//
#include <hip/hip_runtime.h>
#include <hip/hip_fp16.h>
#include <cmath>

typedef float f2 __attribute__((ext_vector_type(2)));

// ---------------- Gaussian windows (host-computed, passed by value) ----------
struct GW7  { float g[7];  };
struct GW11 { float g[11]; };
struct GW29 { float g[29]; };

static void make_gauss(int ws, double sigma, float* out) {
    double t[32]; double s = 0.0;
    int c = ws / 2;
    for (int i = 0; i < ws; ++i) { double d = i - c; t[i] = exp(-(d * d) / (2.0 * sigma * sigma)); s += t[i]; }
    for (int i = 0; i < ws; ++i) out[i] = (float)(t[i] / s);
}

// Accumulator slots (each striped x64 doubles):
// 0-4: ssim[level]  5-9: mcs[level]  10: l1  11: clr  12-27: me1[b]  28-43: me3[b]
#define ACC_SLOTS 44
#define ACC_BYTES (ACC_SLOTS * 64 * sizeof(double))

__device__ __forceinline__ float poly5(float x) {
    float r = fmaf(1.556091f, x, -1.894404f);
    r = fmaf(r, x, 1.435936f);
    r = fmaf(r, x, -0.173433f);
    r = fmaf(r, x, 0.07633f);
    r = fmaf(r, x, -0.000519f);
    return r;
}

__device__ __forceinline__ float border7(int p, const GW7& gw) {
    if (p >= 3 && p <= 508) return 1.f;
    float r = 0.f;
    #pragma unroll
    for (int k = 0; k < 7; ++k) { int q = p + 3 - k; if (q >= 0 && q < 512) r += gw.g[k]; }
    return r;
}

#define SSP 49
#define SRP 33
#define CLINE 33           // clr ring row stride (half2)

// ---------------- SSIM tile: single row-buffer, 4-phase ----------------------
template<bool SRC2, bool INTERIOR>
__device__ __forceinline__ void ssim_tile(
    const float* __restrict__ Aim, const float* __restrict__ Bim,
    const f2* __restrict__ AB, int H, int plane, int ty, int tx,
    const GW11& gw, const GW7& g7, double* __restrict__ acc, int level,
    f2* __restrict__ pooled, int Ho, f2* lds, float* red, int bid)
{
    constexpr int IN = 42;
    f2* s = lds;                                 // load phase: 42 x 49
    f2* r = lds;                                 // conv phases: 42 x 33 (aliased)

    const int tid = threadIdx.x;
    const size_t base = (size_t)plane * H * H;
    const int oy = ty * 32 - 5, ox = tx * 32 - 5;

    // ---- load 42x42 (one magic-div, incremental y/x) ----
    {
        int y = tid / 42;
        int x = tid - y * 42;
        #pragma unroll
        for (int it = 0; it < 7; ++it) {
            if (it < 6 || tid < 228) {
                f2 v;
                if (INTERIOR) {
                    size_t o = base + (size_t)(oy + y) * H + (ox + x);
                    if (SRC2) v = AB[o];
                    else { v.x = Aim[o]; v.y = Bim[o]; }
                } else {
                    int gy = oy + y, gx = ox + x;
                    bool ok = (gy >= 0) && (gy < H) && (gx >= 0) && (gx < H);
                    size_t o = base + (size_t)gy * H + gx;
                    v = (f2){0.f, 0.f};
                    if (ok) { if (SRC2) v = AB[o]; else { v.x = Aim[o]; v.y = Bim[o]; } }
                }
                s[y * SSP + x] = v;
            }
            y += 6; x += 4; if (x >= 42) { x -= 42; ++y; }
        }
    }
    __syncthreads();

    // ---- phase A: snapshot row-conv inputs; pool; L1 (all read s) ----
    f2 v[18];
    const int ry = tid >> 2, rx0 = (tid & 3) * 8;
    if (tid < IN * 4) {
        #pragma unroll
        for (int l = 0; l < 18; ++l) v[l] = s[ry * SSP + rx0 + l];
    }
    if (pooled) {
        int py = tid >> 4, px = tid & 15;
        int a = (5 + 2 * py) * SSP + 5 + 2 * px;
        f2 u = s[a] + s[a + 1] + s[a + SSP] + s[a + SSP + 1];
        pooled[(size_t)plane * Ho * Ho + (size_t)(ty * 16 + py) * Ho + (tx * 16 + px)] = 0.25f * u;
    }
    float l1p = 0.f;
    if (level == 0) {
        #pragma unroll
        for (int jj = 0; jj < 4; ++jj) {
            int p = jj * 256 + tid;
            int py = p >> 5, px = p & 31;
            f2 u = s[(5 + py) * SSP + 5 + px];
            float d = fabsf(u.x - u.y);
            if (INTERIOR) l1p += d;
            else l1p += border7(ty * 32 + py, g7) * border7(tx * 32 + px, g7) * d;
        }
    }
    __syncthreads();   // all s reads done; row buffer may overwrite s

    // ---- B1: row conv of (A,B) ----
    if (tid < IN * 4) {
        #pragma unroll
        for (int j = 0; j < 8; ++j) {
            f2 a = {0.f, 0.f};
            #pragma unroll
            for (int k = 0; k < 11; ++k) a = gw.g[k] * v[j + k] + a;
            r[ry * SRP + rx0 + j] = a;
        }
    }
    __syncthreads();

    // ---- C1: col conv mu (rolling; result stays in registers) ----
    const int y0 = (tid >> 5) * 4, x = tid & 31;
    f2 mu[4];
    #pragma unroll
    for (int j = 0; j < 4; ++j) mu[j] = (f2){0.f, 0.f};
    #pragma unroll
    for (int l = 0; l < 14; ++l) {
        f2 val = r[(y0 + l) * SRP + x];
        #pragma unroll
        for (int j = 0; j < 4; ++j)
            if (l - j >= 0 && l - j < 11) mu[j] = gw.g[l - j] * val + mu[j];
    }
    __syncthreads();

    // ---- B2: squares in place, row conv of (A^2+B^2, A*B) ----
    if (tid < IN * 4) {
        #pragma unroll
        for (int l = 0; l < 18; ++l) {
            f2 w;
            w.x = fmaf(v[l].x, v[l].x, v[l].y * v[l].y);
            w.y = v[l].x * v[l].y;
            v[l] = w;
        }
        #pragma unroll
        for (int j = 0; j < 8; ++j) {
            f2 a = {0.f, 0.f};
            #pragma unroll
            for (int k = 0; k < 11; ++k) a = gw.g[k] * v[j + k] + a;
            r[ry * SRP + rx0 + j] = a;
        }
    }
    __syncthreads();

    // ---- C2: col conv q (rolling) + pointwise ----
    float lss = 0.f, lmc = 0.f;
    {
        f2 q[4];
        #pragma unroll
        for (int j = 0; j < 4; ++j) q[j] = (f2){0.f, 0.f};
        #pragma unroll
        for (int l = 0; l < 14; ++l) {
            f2 val = r[(y0 + l) * SRP + x];
            #pragma unroll
            for (int j = 0; j < 4; ++j)
                if (l - j >= 0 && l - j < 11) q[j] = gw.g[l - j] * val + q[j];
        }
        #pragma unroll
        for (int j = 0; j < 4; ++j) {
            float m1 = mu[j].x, m2 = mu[j].y;
            float P = m1 * m2;
            float S = fmaf(m1, m1, m2 * m2);
            float V1 = 2.f * (q[j].y - P) + 58.5225f;
            float V2 = (q[j].x - S) + 58.5225f;
            float num = (2.f * P + 6.5025f) * V1;
            float SC = S + 6.5025f;
            float inv = __builtin_amdgcn_rcpf(SC * V2);
            lss = fmaf(num, inv, lss);
            lmc = fmaf(V1 * SC, inv, lmc);
        }
    }
    #pragma unroll
    for (int o = 32; o > 0; o >>= 1) {
        lss += __shfl_down(lss, o); lmc += __shfl_down(lmc, o); l1p += __shfl_down(l1p, o);
    }
    if ((tid & 63) == 0) {
        int g = tid >> 6;
        red[g * 3] = lss; red[g * 3 + 1] = lmc; red[g * 3 + 2] = l1p;
    }
    __syncthreads();
    if (tid == 0) {
        float a = red[0] + red[3] + red[6] + red[9];
        float m = red[1] + red[4] + red[7] + red[10];
        int stripe = bid & 63;
        atomicAdd(&acc[(0 + level) * 64 + stripe], (double)a);
        atomicAdd(&acc[(5 + level) * 64 + stripe], (double)m);
        if (level == 0) {
            float l1 = red[2] + red[5] + red[8] + red[11];
            atomicAdd(&acc[10 * 64 + stripe], (double)l1);
        }
    }
}

// ---------------- SSIM levels 2-4 (and fallback L0/L1) -----------------------
template<bool SRC2>
__global__ __launch_bounds__(256) void ssim_kernel(
    const float* __restrict__ Aim, const float* __restrict__ Bim, const f2* __restrict__ AB,
    int H, int tpp, int tilesX, GW11 gw, GW7 g7, double* __restrict__ acc, int level,
    f2* __restrict__ pooled, int Ho)
{
    __shared__ f2 lds[42 * SSP];
    __shared__ float red[12];
    const int bid = blockIdx.x;
    const int plane = bid / tpp;
    const int t = bid - plane * tpp;
    const int ty = t / tilesX, tx = t - ty * tilesX;
    const bool interior = (ty > 0) && (ty < tilesX - 1) && (tx > 0) && (tx < tilesX - 1);
    if (interior)
        ssim_tile<SRC2, true >(Aim, Bim, AB, H, plane, ty, tx, gw, g7, acc, level, pooled, Ho, lds, red, bid);
    else
        ssim_tile<SRC2, false>(Aim, Bim, AB, H, plane, ty, tx, gw, g7, acc, level, pooled, Ho, lds, red, bid);
}

// ---------------- CLR quarter-strip (128-slot half2 ring, 16.9 KB) -----------
template<bool CCLEAN>
__device__ __forceinline__ void clr_strip(
    const float* __restrict__ img1, const float* __restrict__ img3,
    int plane, int tx, int q, const GW29& gw, __half2* buf, float* red,
    double* __restrict__ acc, __half2* __restrict__ pbuf, int bid)
{
    const int tid = threadIdx.x;
    const int base_row = q * 128;                // multiple of 128 -> slot = rel & 127
    const int b = plane / 3, c = plane - b * 3;
    const float wg = (c == 0) ? 0.299f : (c == 1 ? 0.587f : 0.144f);
    const size_t base = (size_t)plane * (512 * 512);
    const int rrow = tid >> 2, xq = tid & 3;
    const int c0 = tx * 8 + xq * 2 - 4;

    auto rowconv = [&](int rel) {
        const int slot = (rel + 128) & 127;
        __half2* dst = buf + slot * CLINE + xq * 8;
        const int lr = base_row + rel;
        if (lr < 0 || lr >= 512) {
            #pragma unroll
            for (int j = 0; j < 8; ++j) dst[j] = __floats2half2_rn(0.f, 0.f);
            return;
        }
        const float4* row1 = (const float4*)(img1 + base + (size_t)lr * 512);
        const float4* row3 = (const float4*)(img3 + base + (size_t)lr * 512);
        float w[40];
        float o1[8];
        #pragma unroll
        for (int k = 0; k < 10; ++k) {
            float4 f;
            if (CCLEAN) f = row1[c0 + k];
            else {
                int cc = c0 + k;
                f = (float4){0.f, 0.f, 0.f, 0.f};
                if (cc >= 0 && cc < 128) f = row1[cc];
            }
            w[4 * k] = f.x; w[4 * k + 1] = f.y; w[4 * k + 2] = f.z; w[4 * k + 3] = f.w;
        }
        #pragma unroll
        for (int j = 0; j < 8; ++j) {
            float a = 0.f;
            #pragma unroll
            for (int k = 0; k < 29; ++k) a = fmaf(gw.g[k], w[2 + j + k], a);
            o1[j] = a;
        }
        #pragma unroll
        for (int k = 0; k < 10; ++k) {
            float4 f;
            if (CCLEAN) f = row3[c0 + k];
            else {
                int cc = c0 + k;
                f = (float4){0.f, 0.f, 0.f, 0.f};
                if (cc >= 0 && cc < 128) f = row3[cc];
            }
            w[4 * k] = f.x; w[4 * k + 1] = f.y; w[4 * k + 2] = f.z; w[4 * k + 3] = f.w;
        }
        #pragma unroll
        for (int j = 0; j < 8; ++j) {
            float a = 0.f;
            #pragma unroll
            for (int k = 0; k < 29; ++k) a = fmaf(gw.g[k], w[2 + j + k], a);
            dst[j] = __floats2half2_rn(o1[j], a);
        }
    };

    rowconv(-14 + rrow);                         // rels -14..49
    __syncthreads();

    float p1 = 0.f, p3 = 0.f;
    const int x = tid & 31;
    #pragma unroll
    for (int ck = 0; ck < 2; ++ck) {
        int rel = 50 + 64 * ck + rrow;           // ck0: 50..113, ck1: 114..141
        if (rel <= 141) rowconv(rel);
        __syncthreads();
        #pragma unroll
        for (int g = 0; g < 2; ++g) {
            const int y0 = 64 * ck + g * 32 + (tid >> 5) * 4;
            f2 mu[4];
            #pragma unroll
            for (int j = 0; j < 4; ++j) mu[j] = (f2){0.f, 0.f};
            #pragma unroll
            for (int l = 0; l < 32; ++l) {
                const int slot = (y0 - 14 + l + 128) & 127;
                float2 tf = __half22float2(buf[slot * CLINE + x]);
                f2 val = {tf.x, tf.y};
                #pragma unroll
                for (int j = 0; j < 4; ++j)
                    if (l - j >= 0 && l - j < 29) mu[j] = gw.g[l - j] * val + mu[j];
            }
            #pragma unroll
            for (int j = 0; j < 4; ++j) {
                float p = poly5(mu[j].x);
                p1 += p; p3 += mu[j].y;
                pbuf[base + (size_t)(base_row + y0 + j) * 512 + (tx * 32 + x)] =
                    __floats2half2_rn(p, mu[j].y);
            }
        }
        if (ck == 0) __syncthreads();            // ring slots reused by ck1 writes
    }

    p1 *= wg; p3 *= wg;
    #pragma unroll
    for (int o = 32; o > 0; o >>= 1) { p1 += __shfl_down(p1, o); p3 += __shfl_down(p3, o); }
    if ((tid & 63) == 0) { red[(tid >> 6) * 2] = p1; red[(tid >> 6) * 2 + 1] = p3; }
    __syncthreads();
    if (tid == 0) {
        float a1 = red[0] + red[2] + red[4] + red[6];
        float a3 = red[1] + red[3] + red[5] + red[7];
        int stripe = bid & 63;
        atomicAdd(&acc[(12 + b) * 64 + stripe], (double)a1);
        atomicAdd(&acc[(28 + b) * 64 + stripe], (double)a3);
    }
}

// ---------------- Fused L0: clr quarter-strips INTERLEAVED with ssim tiles ---
__global__ __launch_bounds__(256) void fused_l0(
    const float* __restrict__ img1, const float* __restrict__ img2,
    const float* __restrict__ img3,
    GW11 g11, GW7 g7, GW29 g29,
    __half2* __restrict__ pbuf, f2* __restrict__ pooled, double* __restrict__ acc)
{
    __shared__ f2 lds[2112];                     // 16.9 KB: ssim 42x49 f2 / clr 128x33 half2
    __shared__ float red[12];
    const int bid = blockIdx.x;
    const int q5 = bid / 5;

    if (bid - q5 * 5 == 0) {
        // clr block: cid in [0, 3072)
        const int cid = q5;
        __half2* buf = (__half2*)lds;
        const int plane = cid >> 6, rr = cid & 63;
        const int tx = rr >> 2, q = rr & 3;
        if (tx >= 1 && tx <= 14)
            clr_strip<true >(img1, img3, plane, tx, q, g29, buf, red, acc, pbuf, bid);
        else
            clr_strip<false>(img1, img3, plane, tx, q, g29, buf, red, acc, pbuf, bid);
        return;
    }

    // ssim block: sid in [0, 12288)
    const int sid = bid - q5 - 1;
    const int plane = sid >> 8;
    const int t = sid & 255;
    const int ty = t >> 4, tx = t & 15;
    const bool interior = (ty >= 1) && (ty <= 14) && (tx >= 1) && (tx <= 14);
    if (interior)
        ssim_tile<false, true >(img1, img2, nullptr, 512, plane, ty, tx, g11, g7, acc, 0, pooled, 256, lds, red, bid);
    else
        ssim_tile<false, false>(img1, img2, nullptr, 512, plane, ty, tx, g11, g7, acc, 0, pooled, 256, lds, red, bid);
}

// ---------------- Fused L1: clr_fin chunks INTERLEAVED with ssim L1 tiles ----
// Even bids: clr_fin chunk (streams pbuf, memory-bound). Odd bids: ssim L1
// tile (VALU-bound). Complementary regimes overlap on each CU; both depend
// only on fused_l0's outputs (stream-ordered).
__global__ __launch_bounds__(256) void fused_l1(
    const f2* __restrict__ AB1, f2* __restrict__ pooled2,
    const __half2* __restrict__ pbuf,
    GW11 g11, GW7 g7, double* __restrict__ acc)
{
    __shared__ f2 lds[42 * SSP];
    __shared__ float red[12];
    __shared__ float sc_sh;
    const int bid = blockIdx.x;
    const int tid = threadIdx.x;

    if ((bid & 1) == 0) {
        // ---- clr_fin chunk: cid in [0, 3072) ----
        const int cid = bid >> 1;
        const int b = cid / 192, sub = cid - b * 192;
        if (tid < 64) {
            double m1 = acc[(12 + b) * 64 + tid];
            double m3 = acc[(28 + b) * 64 + tid];
            #pragma unroll
            for (int o = 32; o > 0; o >>= 1) { m1 += __shfl_down(m1, o); m3 += __shfl_down(m3, o); }
            if (tid == 0) sc_sh = (float)(m1 / m3);
        }
        __syncthreads();
        const float sc = sc_sh;
        const size_t bo = (size_t)b * 786432 + (size_t)sub * 4096;
        float s = 0.f;
        #pragma unroll
        for (int it = 0; it < 8; ++it) {
            size_t i = bo + it * 512 + tid * 2;
            float2 a = __half22float2(pbuf[i]);
            float2 c = __half22float2(pbuf[i + 1]);
            s += fabsf(a.x - a.y * sc) + fabsf(c.x - c.y * sc);
        }
        #pragma unroll
        for (int o = 32; o > 0; o >>= 1) s += __shfl_down(s, o);
        if ((tid & 63) == 0) red[tid >> 6] = s;
        __syncthreads();
        if (tid == 0)
            atomicAdd(&acc[11 * 64 + (bid & 63)], (double)(red[0] + red[1] + red[2] + red[3]));
        return;
    }

    // ---- ssim L1 tile: sid in [0, 3072) ----
    const int sid = bid >> 1;
    const int plane = sid >> 6;
    const int t = sid & 63;
    const int ty = t >> 3, tx = t & 7;
    const bool interior = (ty >= 1) && (ty <= 6) && (tx >= 1) && (tx <= 6);
    if (interior)
        ssim_tile<true, true >(nullptr, nullptr, AB1, 256, plane, ty, tx, g11, g7, acc, 1, pooled2, 128, lds, red, bid);
    else
        ssim_tile<true, false>(nullptr, nullptr, AB1, 256, plane, ty, tx, g11, g7, acc, 1, pooled2, 128, lds, red, bid);
}

// ---------------- CLR fallback: full-strip ring (modes 1/2, small ws) --------
#define CRP 33
#define RING 128
template<int MODE>
__global__ __launch_bounds__(256) void clr_conv(
    const float* __restrict__ img1, const float* __restrict__ img3,
    __half2* __restrict__ pbuf, GW29 gw, double* __restrict__ acc)
{
    __shared__ f2 r[RING * CRP];
    __shared__ float red[8];
    __shared__ float sc_sh;

    const int tid = threadIdx.x, bid = blockIdx.x;
    const int plane = bid >> 4, tx = bid & 15;
    const int b = plane / 3, c = plane - b * 3;
    const float wg = (c == 0) ? 0.299f : (c == 1 ? 0.587f : 0.144f);
    const size_t base = (size_t)plane * (512 * 512);

    if (MODE == 2 && tid < 64) {
        double m1 = acc[(12 + b) * 64 + tid];
        double m3 = acc[(28 + b) * 64 + tid];
        #pragma unroll
        for (int o = 32; o > 0; o >>= 1) { m1 += __shfl_down(m1, o); m3 += __shfl_down(m3, o); }
        if (tid == 0) sc_sh = (float)(m1 / m3);
    }

    const int rrow = tid >> 2, xq = tid & 3;
    const int c0 = tx * 8 + xq * 2 - 4;

    auto rowconv = [&](int lr) {
        const int ri = ((lr + RING) & (RING - 1)) * CRP + xq * 8;
        if (lr < 0 || lr >= 512) {
            #pragma unroll
            for (int j = 0; j < 8; ++j) r[ri + j] = (f2){0.f, 0.f};
            return;
        }
        const float4* row1 = (const float4*)(img1 + base + (size_t)lr * 512);
        const float4* row3 = (const float4*)(img3 + base + (size_t)lr * 512);
        float w[40];
        float o1[8];
        #pragma unroll
        for (int k = 0; k < 10; ++k) {
            int cc = c0 + k;
            float4 f = {0.f, 0.f, 0.f, 0.f};
            if (cc >= 0 && cc < 128) f = row1[cc];
            w[4 * k] = f.x; w[4 * k + 1] = f.y; w[4 * k + 2] = f.z; w[4 * k + 3] = f.w;
        }
        #pragma unroll
        for (int j = 0; j < 8; ++j) {
            float a = 0.f;
            #pragma unroll
            for (int k = 0; k < 29; ++k) a = fmaf(gw.g[k], w[2 + j + k], a);
            o1[j] = a;
        }
        #pragma unroll
        for (int k = 0; k < 10; ++k) {
            int cc = c0 + k;
            float4 f = {0.f, 0.f, 0.f, 0.f};
            if (cc >= 0 && cc < 128) f = row3[cc];
            w[4 * k] = f.x; w[4 * k + 1] = f.y; w[4 * k + 2] = f.z; w[4 * k + 3] = f.w;
        }
        #pragma unroll
        for (int j = 0; j < 8; ++j) {
            float a = 0.f;
            #pragma unroll
            for (int k = 0; k < 29; ++k) a = fmaf(gw.g[k], w[2 + j + k], a);
            r[ri + j] = (f2){o1[j], a};
        }
    };

    rowconv(-14 + rrow);
    __syncthreads();

    float p1 = 0.f, p3 = 0.f;
    const int x = tid & 31;
    #pragma unroll 1
    for (int ck = 0; ck < 8; ++ck) {
        {
            int lr = 50 + 64 * ck + rrow;
            if (lr <= 525) rowconv(lr);
        }
        __syncthreads();
        #pragma unroll
        for (int g = 0; g < 2; ++g) {
            const int y0 = 64 * ck + g * 32 + (tid >> 5) * 4;
            f2 mu[4];
            #pragma unroll
            for (int j = 0; j < 4; ++j) mu[j] = (f2){0.f, 0.f};
            #pragma unroll
            for (int l = 0; l < 32; ++l) {
                f2 val = r[(((y0 - 14 + l) + RING) & (RING - 1)) * CRP + x];
                #pragma unroll
                for (int j = 0; j < 4; ++j)
                    if (l - j >= 0 && l - j < 29) mu[j] = gw.g[l - j] * val + mu[j];
            }
            #pragma unroll
            for (int j = 0; j < 4; ++j) {
                float p = poly5(mu[j].x);
                if (MODE == 2) {
                    p1 += fabsf(p - mu[j].y * sc_sh);
                } else {
                    p1 += p; p3 += mu[j].y;
                }
            }
        }
        if (ck < 7) __syncthreads();
    }

    if (MODE != 2) { p1 *= wg; p3 *= wg; }
    #pragma unroll
    for (int o = 32; o > 0; o >>= 1) { p1 += __shfl_down(p1, o); p3 += __shfl_down(p3, o); }
    if ((tid & 63) == 0) { red[(tid >> 6) * 2] = p1; red[(tid >> 6) * 2 + 1] = p3; }
    __syncthreads();
    if (tid == 0) {
        float a1 = red[0] + red[2] + red[4] + red[6];
        int stripe = bid & 63;
        if (MODE == 2) {
            atomicAdd(&acc[11 * 64 + stripe], (double)a1);
        } else {
            float a3 = red[1] + red[3] + red[5] + red[7];
            atomicAdd(&acc[(12 + b) * 64 + stripe], (double)a1);
            atomicAdd(&acc[(28 + b) * 64 + stripe], (double)a3);
        }
    }
}

// ---------------- Finalize: combine everything into the scalar ---------------
__global__ void finalize_kernel(const double* __restrict__ acc, float* __restrict__ out)
{
    __shared__ double sums[ACC_SLOTS];
    int t = threadIdx.x;
    if (t < ACC_SLOTS) {
        double s = 0.0;
        for (int i = 0; i < 64; ++i) s += acc[t * 64 + i];
        sums[t] = s;
    }
    __syncthreads();
    if (t == 0) {
        const double w[5] = {0.0448, 0.2856, 0.3001, 0.2363, 0.1333};
        double value = 1.0;
        for (int l = 0; l < 5; ++l) {
            double dim = (double)(512 >> l);
            double cnt = 48.0 * dim * dim;
            double mval = (l < 4) ? (sums[5 + l] / cnt) : (sums[l] / cnt);
            value *= pow(mval, w[l]);
        }
        double n0 = 48.0 * 512.0 * 512.0;
        double l1v = sums[10] / n0;
        double clrv = sums[11] / n0;
        out[0] = (float)(0.4 * (1.0 - value) + 0.4 * l1v + 0.2 * clrv);
    }
}

// ---------------- Launch ------------------------------------------------------
extern "C" void kernel_launch(void* const* d_in, const int* in_sizes, int n_in,
                              void* d_out, int out_size, void* d_ws, size_t ws_size,
                              hipStream_t stream)
{
    (void)in_sizes; (void)n_in; (void)out_size;
    const float* img1 = (const float*)d_in[0];
    const float* img2 = (const float*)d_in[1];
    const float* img3 = (const float*)d_in[2];
    float* out = (float*)d_out;
    double* acc = (double*)d_ws;

    GW11 g11; make_gauss(11, 1.5, g11.g);
    GW7  g7;  make_gauss(7, 1.1, g7.g);
    GW29 g29; make_gauss(29, 29.0 / 6.0, g29.g);

    hipMemsetAsync(d_ws, 0, ACC_BYTES, stream);

    // Interleaved (A,B) float2 pyramid for levels 1..4
    f2* pyr = (f2*)((char*)d_ws + 32768);
    size_t offs[4];
    offs[0] = 0;
    offs[1] = offs[0] + (size_t)48 * 256 * 256;
    offs[2] = offs[1] + (size_t)48 * 128 * 128;
    offs[3] = offs[2] + (size_t)48 * 64 * 64;
    const size_t PYRF2 = offs[3] + (size_t)48 * 32 * 32;

    const size_t poff = 32768 + PYRF2 * sizeof(f2);
    const size_t PBYTES = (size_t)48 * 512 * 512 * sizeof(__half2);
    __half2* pbuf = (__half2*)((char*)d_ws + poff);
    const bool bigws = (ws_size >= poff + PBYTES);

    if (bigws) {
        fused_l0<<<15360, 256, 0, stream>>>(img1, img2, img3, g11, g7, g29,
                                            pbuf, pyr + offs[0], acc);
        // L1 + clr_fin fused (complementary regimes, 1:1 interleave)
        fused_l1<<<6144, 256, 0, stream>>>(pyr + offs[0], pyr + offs[1], pbuf,
                                           g11, g7, acc);
        // Levels 2..4
        const f2* cur = pyr + offs[1];
        int H = 128;
        for (int l = 2; l < 5; ++l) {
            int tilesX = H / 32; int tpp = tilesX * tilesX;
            f2* pooled = (l < 4) ? (pyr + offs[l]) : nullptr;
            int Ho = H / 2;
            ssim_kernel<true><<<48 * tpp, 256, 0, stream>>>(
                nullptr, nullptr, cur, H, tpp, tilesX, g11, g7, acc, l, pooled, Ho);
            cur = pooled; H = Ho;
        }
    } else {
        ssim_kernel<false><<<12288, 256, 0, stream>>>(
            img1, img2, nullptr, 512, 256, 16, g11, g7, acc, 0, pyr + offs[0], 256);
        clr_conv<1><<<768, 256, 0, stream>>>(img1, img3, pbuf, g29, acc);
        const f2* cur = pyr + offs[0];
        int H = 256;
        for (int l = 1; l < 5; ++l) {
            int tilesX = H / 32; int tpp = tilesX * tilesX;
            f2* pooled = (l < 4) ? (pyr + offs[l]) : nullptr;
            int Ho = H / 2;
            ssim_kernel<true><<<48 * tpp, 256, 0, stream>>>(
                nullptr, nullptr, cur, H, tpp, tilesX, g11, g7, acc, l, pooled, Ho);
            cur = pooled; H = Ho;
        }
        clr_conv<2><<<768, 256, 0, stream>>>(img1, img3, pbuf, g29, acc);
    }

    finalize_kernel<<<1, 64, 0, stream>>>(acc, out);
}

// Round 16
// 199.658 us; speedup vs baseline: 1.1185x; 1.0446x over previous
//
#include <hip/hip_runtime.h>
#include <hip/hip_fp16.h>
#include <cmath>

typedef float f2 __attribute__((ext_vector_type(2)));

// ---------------- Gaussian windows (host-computed, passed by value) ----------
struct GW7  { float g[7];  };
struct GW11 { float g[11]; };
struct GW29 { float g[29]; };

static void make_gauss(int ws, double sigma, float* out) {
    double t[32]; double s = 0.0;
    int c = ws / 2;
    for (int i = 0; i < ws; ++i) { double d = i - c; t[i] = exp(-(d * d) / (2.0 * sigma * sigma)); s += t[i]; }
    for (int i = 0; i < ws; ++i) out[i] = (float)(t[i] / s);
}

// Accumulator slots (each striped x64 doubles):
// 0-4: ssim[level]  5-9: mcs[level]  10: l1  11: clr  12-27: me1[b]  28-43: me3[b]
#define ACC_SLOTS 44
#define ACC_BYTES (ACC_SLOTS * 64 * sizeof(double))

__device__ __forceinline__ float poly5(float x) {
    float r = fmaf(1.556091f, x, -1.894404f);
    r = fmaf(r, x, 1.435936f);
    r = fmaf(r, x, -0.173433f);
    r = fmaf(r, x, 0.07633f);
    r = fmaf(r, x, -0.000519f);
    return r;
}

__device__ __forceinline__ float border7(int p, const GW7& gw) {
    if (p >= 3 && p <= 508) return 1.f;
    float r = 0.f;
    #pragma unroll
    for (int k = 0; k < 7; ++k) { int q = p + 3 - k; if (q >= 0 && q < 512) r += gw.g[k]; }
    return r;
}

#define SSP 49
#define SRP 33
#define CLINE 33           // clr ring row stride (half2)

// ---------------- SSIM tile: single row-buffer, 4-phase ----------------------
template<bool SRC2, bool INTERIOR>
__device__ __forceinline__ void ssim_tile(
    const float* __restrict__ Aim, const float* __restrict__ Bim,
    const f2* __restrict__ AB, int H, int plane, int ty, int tx,
    const GW11& gw, const GW7& g7, double* __restrict__ acc, int level,
    f2* __restrict__ pooled, int Ho, f2* lds, float* red, int bid)
{
    constexpr int IN = 42;
    f2* s = lds;                                 // load phase: 42 x 49
    f2* r = lds;                                 // conv phases: 42 x 33 (aliased)

    const int tid = threadIdx.x;
    const size_t base = (size_t)plane * H * H;
    const int oy = ty * 32 - 5, ox = tx * 32 - 5;

    // ---- load 42x42 (one magic-div, incremental y/x) ----
    {
        int y = tid / 42;
        int x = tid - y * 42;
        #pragma unroll
        for (int it = 0; it < 7; ++it) {
            if (it < 6 || tid < 228) {
                f2 v;
                if (INTERIOR) {
                    size_t o = base + (size_t)(oy + y) * H + (ox + x);
                    if (SRC2) v = AB[o];
                    else { v.x = Aim[o]; v.y = Bim[o]; }
                } else {
                    int gy = oy + y, gx = ox + x;
                    bool ok = (gy >= 0) && (gy < H) && (gx >= 0) && (gx < H);
                    size_t o = base + (size_t)gy * H + gx;
                    v = (f2){0.f, 0.f};
                    if (ok) { if (SRC2) v = AB[o]; else { v.x = Aim[o]; v.y = Bim[o]; } }
                }
                s[y * SSP + x] = v;
            }
            y += 6; x += 4; if (x >= 42) { x -= 42; ++y; }
        }
    }
    __syncthreads();

    // ---- phase A: snapshot row-conv inputs; pool; L1 (all read s) ----
    f2 v[18];
    const int ry = tid >> 2, rx0 = (tid & 3) * 8;
    if (tid < IN * 4) {
        #pragma unroll
        for (int l = 0; l < 18; ++l) v[l] = s[ry * SSP + rx0 + l];
    }
    if (pooled) {
        int py = tid >> 4, px = tid & 15;
        int a = (5 + 2 * py) * SSP + 5 + 2 * px;
        f2 u = s[a] + s[a + 1] + s[a + SSP] + s[a + SSP + 1];
        pooled[(size_t)plane * Ho * Ho + (size_t)(ty * 16 + py) * Ho + (tx * 16 + px)] = 0.25f * u;
    }
    float l1p = 0.f;
    if (level == 0) {
        #pragma unroll
        for (int jj = 0; jj < 4; ++jj) {
            int p = jj * 256 + tid;
            int py = p >> 5, px = p & 31;
            f2 u = s[(5 + py) * SSP + 5 + px];
            float d = fabsf(u.x - u.y);
            if (INTERIOR) l1p += d;
            else l1p += border7(ty * 32 + py, g7) * border7(tx * 32 + px, g7) * d;
        }
    }
    __syncthreads();   // all s reads done; row buffer may overwrite s

    // ---- B1: row conv of (A,B) ----
    if (tid < IN * 4) {
        #pragma unroll
        for (int j = 0; j < 8; ++j) {
            f2 a = {0.f, 0.f};
            #pragma unroll
            for (int k = 0; k < 11; ++k) a = gw.g[k] * v[j + k] + a;
            r[ry * SRP + rx0 + j] = a;
        }
    }
    __syncthreads();

    // ---- C1: col conv mu (rolling; result stays in registers) ----
    const int y0 = (tid >> 5) * 4, x = tid & 31;
    f2 mu[4];
    #pragma unroll
    for (int j = 0; j < 4; ++j) mu[j] = (f2){0.f, 0.f};
    #pragma unroll
    for (int l = 0; l < 14; ++l) {
        f2 val = r[(y0 + l) * SRP + x];
        #pragma unroll
        for (int j = 0; j < 4; ++j)
            if (l - j >= 0 && l - j < 11) mu[j] = gw.g[l - j] * val + mu[j];
    }
    __syncthreads();

    // ---- B2: squares in place, row conv of (A^2+B^2, A*B) ----
    if (tid < IN * 4) {
        #pragma unroll
        for (int l = 0; l < 18; ++l) {
            f2 w;
            w.x = fmaf(v[l].x, v[l].x, v[l].y * v[l].y);
            w.y = v[l].x * v[l].y;
            v[l] = w;
        }
        #pragma unroll
        for (int j = 0; j < 8; ++j) {
            f2 a = {0.f, 0.f};
            #pragma unroll
            for (int k = 0; k < 11; ++k) a = gw.g[k] * v[j + k] + a;
            r[ry * SRP + rx0 + j] = a;
        }
    }
    __syncthreads();

    // ---- C2: col conv q (rolling) + pointwise ----
    float lss = 0.f, lmc = 0.f;
    {
        f2 q[4];
        #pragma unroll
        for (int j = 0; j < 4; ++j) q[j] = (f2){0.f, 0.f};
        #pragma unroll
        for (int l = 0; l < 14; ++l) {
            f2 val = r[(y0 + l) * SRP + x];
            #pragma unroll
            for (int j = 0; j < 4; ++j)
                if (l - j >= 0 && l - j < 11) q[j] = gw.g[l - j] * val + q[j];
        }
        #pragma unroll
        for (int j = 0; j < 4; ++j) {
            float m1 = mu[j].x, m2 = mu[j].y;
            float P = m1 * m2;
            float S = fmaf(m1, m1, m2 * m2);
            float V1 = 2.f * (q[j].y - P) + 58.5225f;
            float V2 = (q[j].x - S) + 58.5225f;
            float num = (2.f * P + 6.5025f) * V1;
            float SC = S + 6.5025f;
            float inv = __builtin_amdgcn_rcpf(SC * V2);
            lss = fmaf(num, inv, lss);
            lmc = fmaf(V1 * SC, inv, lmc);
        }
    }
    #pragma unroll
    for (int o = 32; o > 0; o >>= 1) {
        lss += __shfl_down(lss, o); lmc += __shfl_down(lmc, o); l1p += __shfl_down(l1p, o);
    }
    if ((tid & 63) == 0) {
        int g = tid >> 6;
        red[g * 3] = lss; red[g * 3 + 1] = lmc; red[g * 3 + 2] = l1p;
    }
    __syncthreads();
    if (tid == 0) {
        float a = red[0] + red[3] + red[6] + red[9];
        float m = red[1] + red[4] + red[7] + red[10];
        int stripe = bid & 63;
        atomicAdd(&acc[(0 + level) * 64 + stripe], (double)a);
        atomicAdd(&acc[(5 + level) * 64 + stripe], (double)m);
        if (level == 0) {
            float l1 = red[2] + red[5] + red[8] + red[11];
            atomicAdd(&acc[10 * 64 + stripe], (double)l1);
        }
    }
}

// ---------------- SSIM levels 2-4 (and fallback L0/L1) -----------------------
template<bool SRC2>
__global__ __launch_bounds__(256) void ssim_kernel(
    const float* __restrict__ Aim, const float* __restrict__ Bim, const f2* __restrict__ AB,
    int H, int tpp, int tilesX, GW11 gw, GW7 g7, double* __restrict__ acc, int level,
    f2* __restrict__ pooled, int Ho)
{
    __shared__ f2 lds[42 * SSP];
    __shared__ float red[12];
    const int bid = blockIdx.x;
    const int plane = bid / tpp;
    const int t = bid - plane * tpp;
    const int ty = t / tilesX, tx = t - ty * tilesX;
    const bool interior = (ty > 0) && (ty < tilesX - 1) && (tx > 0) && (tx < tilesX - 1);
    if (interior)
        ssim_tile<SRC2, true >(Aim, Bim, AB, H, plane, ty, tx, gw, g7, acc, level, pooled, Ho, lds, red, bid);
    else
        ssim_tile<SRC2, false>(Aim, Bim, AB, H, plane, ty, tx, gw, g7, acc, level, pooled, Ho, lds, red, bid);
}

// ---------------- CLR quarter-strip (128-slot half2 ring, 16.9 KB) -----------
template<bool CCLEAN>
__device__ __forceinline__ void clr_strip(
    const float* __restrict__ img1, const float* __restrict__ img3,
    int plane, int tx, int q, const GW29& gw, __half2* buf, float* red,
    double* __restrict__ acc, __half2* __restrict__ pbuf, int bid)
{
    const int tid = threadIdx.x;
    const int base_row = q * 128;                // multiple of 128 -> slot = rel & 127
    const int b = plane / 3, c = plane - b * 3;
    const float wg = (c == 0) ? 0.299f : (c == 1 ? 0.587f : 0.144f);
    const size_t base = (size_t)plane * (512 * 512);
    const int rrow = tid >> 2, xq = tid & 3;
    const int c0 = tx * 8 + xq * 2 - 4;

    auto rowconv = [&](int rel) {
        const int slot = (rel + 128) & 127;
        __half2* dst = buf + slot * CLINE + xq * 8;
        const int lr = base_row + rel;
        if (lr < 0 || lr >= 512) {
            #pragma unroll
            for (int j = 0; j < 8; ++j) dst[j] = __floats2half2_rn(0.f, 0.f);
            return;
        }
        const float4* row1 = (const float4*)(img1 + base + (size_t)lr * 512);
        const float4* row3 = (const float4*)(img3 + base + (size_t)lr * 512);
        float w[40];
        float o1[8];
        #pragma unroll
        for (int k = 0; k < 10; ++k) {
            float4 f;
            if (CCLEAN) f = row1[c0 + k];
            else {
                int cc = c0 + k;
                f = (float4){0.f, 0.f, 0.f, 0.f};
                if (cc >= 0 && cc < 128) f = row1[cc];
            }
            w[4 * k] = f.x; w[4 * k + 1] = f.y; w[4 * k + 2] = f.z; w[4 * k + 3] = f.w;
        }
        #pragma unroll
        for (int j = 0; j < 8; ++j) {
            float a = 0.f;
            #pragma unroll
            for (int k = 0; k < 29; ++k) a = fmaf(gw.g[k], w[2 + j + k], a);
            o1[j] = a;
        }
        #pragma unroll
        for (int k = 0; k < 10; ++k) {
            float4 f;
            if (CCLEAN) f = row3[c0 + k];
            else {
                int cc = c0 + k;
                f = (float4){0.f, 0.f, 0.f, 0.f};
                if (cc >= 0 && cc < 128) f = row3[cc];
            }
            w[4 * k] = f.x; w[4 * k + 1] = f.y; w[4 * k + 2] = f.z; w[4 * k + 3] = f.w;
        }
        #pragma unroll
        for (int j = 0; j < 8; ++j) {
            float a = 0.f;
            #pragma unroll
            for (int k = 0; k < 29; ++k) a = fmaf(gw.g[k], w[2 + j + k], a);
            dst[j] = __floats2half2_rn(o1[j], a);
        }
    };

    rowconv(-14 + rrow);                         // rels -14..49
    __syncthreads();

    float p1 = 0.f, p3 = 0.f;
    const int x = tid & 31;
    #pragma unroll
    for (int ck = 0; ck < 2; ++ck) {
        int rel = 50 + 64 * ck + rrow;           // ck0: 50..113, ck1: 114..141
        if (rel <= 141) rowconv(rel);
        __syncthreads();
        #pragma unroll
        for (int g = 0; g < 2; ++g) {
            const int y0 = 64 * ck + g * 32 + (tid >> 5) * 4;
            f2 mu[4];
            #pragma unroll
            for (int j = 0; j < 4; ++j) mu[j] = (f2){0.f, 0.f};
            #pragma unroll
            for (int l = 0; l < 32; ++l) {
                const int slot = (y0 - 14 + l + 128) & 127;
                float2 tf = __half22float2(buf[slot * CLINE + x]);
                f2 val = {tf.x, tf.y};
                #pragma unroll
                for (int j = 0; j < 4; ++j)
                    if (l - j >= 0 && l - j < 29) mu[j] = gw.g[l - j] * val + mu[j];
            }
            #pragma unroll
            for (int j = 0; j < 4; ++j) {
                float p = poly5(mu[j].x);
                p1 += p; p3 += mu[j].y;
                pbuf[base + (size_t)(base_row + y0 + j) * 512 + (tx * 32 + x)] =
                    __floats2half2_rn(p, mu[j].y);
            }
        }
        if (ck == 0) __syncthreads();            // ring slots reused by ck1 writes
    }

    p1 *= wg; p3 *= wg;
    #pragma unroll
    for (int o = 32; o > 0; o >>= 1) { p1 += __shfl_down(p1, o); p3 += __shfl_down(p3, o); }
    if ((tid & 63) == 0) { red[(tid >> 6) * 2] = p1; red[(tid >> 6) * 2 + 1] = p3; }
    __syncthreads();
    if (tid == 0) {
        float a1 = red[0] + red[2] + red[4] + red[6];
        float a3 = red[1] + red[3] + red[5] + red[7];
        int stripe = bid & 63;
        atomicAdd(&acc[(12 + b) * 64 + stripe], (double)a1);
        atomicAdd(&acc[(28 + b) * 64 + stripe], (double)a3);
    }
}

// ---------------- Fused L0: XCD-chunked swizzle + 1:5 clr/ssim interleave ----
// Consecutive hardware blockIdx values round-robin across the 8 XCDs; the
// chunked swizzle gives each XCD a CONTIGUOUS range of work ids so tiles that
// share halo rows resolve in the same XCD's L2 instead of re-fetching
// (r15 FETCH 275 MB vs ~155 MB unique data). 15360 % 8 == 0 -> bijective.
__global__ __launch_bounds__(256) void fused_l0(
    const float* __restrict__ img1, const float* __restrict__ img2,
    const float* __restrict__ img3,
    GW11 g11, GW7 g7, GW29 g29,
    __half2* __restrict__ pbuf, f2* __restrict__ pooled, double* __restrict__ acc)
{
    __shared__ f2 lds[2112];                     // 16.9 KB: ssim 42x49 f2 / clr 128x33 half2
    __shared__ float red[12];
    const int bid0 = blockIdx.x;
    const int bid = (bid0 & 7) * 1920 + (bid0 >> 3);   // XCD-chunked work id
    const int q5 = bid / 5;

    if (bid - q5 * 5 == 0) {
        // clr block: cid in [0, 3072)
        const int cid = q5;
        __half2* buf = (__half2*)lds;
        const int plane = cid >> 6, rr = cid & 63;
        const int tx = rr >> 2, q = rr & 3;
        if (tx >= 1 && tx <= 14)
            clr_strip<true >(img1, img3, plane, tx, q, g29, buf, red, acc, pbuf, bid);
        else
            clr_strip<false>(img1, img3, plane, tx, q, g29, buf, red, acc, pbuf, bid);
        return;
    }

    // ssim block: sid in [0, 12288)
    const int sid = bid - q5 - 1;
    const int plane = sid >> 8;
    const int t = sid & 255;
    const int ty = t >> 4, tx = t & 15;
    const bool interior = (ty >= 1) && (ty <= 14) && (tx >= 1) && (tx <= 14);
    if (interior)
        ssim_tile<false, true >(img1, img2, nullptr, 512, plane, ty, tx, g11, g7, acc, 0, pooled, 256, lds, red, bid);
    else
        ssim_tile<false, false>(img1, img2, nullptr, 512, plane, ty, tx, g11, g7, acc, 0, pooled, 256, lds, red, bid);
}

// ---------------- Fused L1: clr_fin chunks INTERLEAVED with ssim L1 tiles ----
__global__ __launch_bounds__(256) void fused_l1(
    const f2* __restrict__ AB1, f2* __restrict__ pooled2,
    const __half2* __restrict__ pbuf,
    GW11 g11, GW7 g7, double* __restrict__ acc)
{
    __shared__ f2 lds[42 * SSP];
    __shared__ float red[12];
    __shared__ float sc_sh;
    const int bid = blockIdx.x;
    const int tid = threadIdx.x;

    if ((bid & 1) == 0) {
        // ---- clr_fin chunk: cid in [0, 3072) ----
        const int cid = bid >> 1;
        const int b = cid / 192, sub = cid - b * 192;
        if (tid < 64) {
            double m1 = acc[(12 + b) * 64 + tid];
            double m3 = acc[(28 + b) * 64 + tid];
            #pragma unroll
            for (int o = 32; o > 0; o >>= 1) { m1 += __shfl_down(m1, o); m3 += __shfl_down(m3, o); }
            if (tid == 0) sc_sh = (float)(m1 / m3);
        }
        __syncthreads();
        const float sc = sc_sh;
        const size_t bo = (size_t)b * 786432 + (size_t)sub * 4096;
        float s = 0.f;
        #pragma unroll
        for (int it = 0; it < 8; ++it) {
            size_t i = bo + it * 512 + tid * 2;
            float2 a = __half22float2(pbuf[i]);
            float2 c = __half22float2(pbuf[i + 1]);
            s += fabsf(a.x - a.y * sc) + fabsf(c.x - c.y * sc);
        }
        #pragma unroll
        for (int o = 32; o > 0; o >>= 1) s += __shfl_down(s, o);
        if ((tid & 63) == 0) red[tid >> 6] = s;
        __syncthreads();
        if (tid == 0)
            atomicAdd(&acc[11 * 64 + (bid & 63)], (double)(red[0] + red[1] + red[2] + red[3]));
        return;
    }

    // ---- ssim L1 tile: sid in [0, 3072) ----
    const int sid = bid >> 1;
    const int plane = sid >> 6;
    const int t = sid & 63;
    const int ty = t >> 3, tx = t & 7;
    const bool interior = (ty >= 1) && (ty <= 6) && (tx >= 1) && (tx <= 6);
    if (interior)
        ssim_tile<true, true >(nullptr, nullptr, AB1, 256, plane, ty, tx, g11, g7, acc, 1, pooled2, 128, lds, red, bid);
    else
        ssim_tile<true, false>(nullptr, nullptr, AB1, 256, plane, ty, tx, g11, g7, acc, 1, pooled2, 128, lds, red, bid);
}

// ---------------- CLR fallback: full-strip ring (modes 1/2, small ws) --------
#define CRP 33
#define RING 128
template<int MODE>
__global__ __launch_bounds__(256) void clr_conv(
    const float* __restrict__ img1, const float* __restrict__ img3,
    __half2* __restrict__ pbuf, GW29 gw, double* __restrict__ acc)
{
    __shared__ f2 r[RING * CRP];
    __shared__ float red[8];
    __shared__ float sc_sh;

    const int tid = threadIdx.x, bid = blockIdx.x;
    const int plane = bid >> 4, tx = bid & 15;
    const int b = plane / 3, c = plane - b * 3;
    const float wg = (c == 0) ? 0.299f : (c == 1 ? 0.587f : 0.144f);
    const size_t base = (size_t)plane * (512 * 512);

    if (MODE == 2 && tid < 64) {
        double m1 = acc[(12 + b) * 64 + tid];
        double m3 = acc[(28 + b) * 64 + tid];
        #pragma unroll
        for (int o = 32; o > 0; o >>= 1) { m1 += __shfl_down(m1, o); m3 += __shfl_down(m3, o); }
        if (tid == 0) sc_sh = (float)(m1 / m3);
    }

    const int rrow = tid >> 2, xq = tid & 3;
    const int c0 = tx * 8 + xq * 2 - 4;

    auto rowconv = [&](int lr) {
        const int ri = ((lr + RING) & (RING - 1)) * CRP + xq * 8;
        if (lr < 0 || lr >= 512) {
            #pragma unroll
            for (int j = 0; j < 8; ++j) r[ri + j] = (f2){0.f, 0.f};
            return;
        }
        const float4* row1 = (const float4*)(img1 + base + (size_t)lr * 512);
        const float4* row3 = (const float4*)(img3 + base + (size_t)lr * 512);
        float w[40];
        float o1[8];
        #pragma unroll
        for (int k = 0; k < 10; ++k) {
            int cc = c0 + k;
            float4 f = {0.f, 0.f, 0.f, 0.f};
            if (cc >= 0 && cc < 128) f = row1[cc];
            w[4 * k] = f.x; w[4 * k + 1] = f.y; w[4 * k + 2] = f.z; w[4 * k + 3] = f.w;
        }
        #pragma unroll
        for (int j = 0; j < 8; ++j) {
            float a = 0.f;
            #pragma unroll
            for (int k = 0; k < 29; ++k) a = fmaf(gw.g[k], w[2 + j + k], a);
            o1[j] = a;
        }
        #pragma unroll
        for (int k = 0; k < 10; ++k) {
            int cc = c0 + k;
            float4 f = {0.f, 0.f, 0.f, 0.f};
            if (cc >= 0 && cc < 128) f = row3[cc];
            w[4 * k] = f.x; w[4 * k + 1] = f.y; w[4 * k + 2] = f.z; w[4 * k + 3] = f.w;
        }
        #pragma unroll
        for (int j = 0; j < 8; ++j) {
            float a = 0.f;
            #pragma unroll
            for (int k = 0; k < 29; ++k) a = fmaf(gw.g[k], w[2 + j + k], a);
            r[ri + j] = (f2){o1[j], a};
        }
    };

    rowconv(-14 + rrow);
    __syncthreads();

    float p1 = 0.f, p3 = 0.f;
    const int x = tid & 31;
    #pragma unroll 1
    for (int ck = 0; ck < 8; ++ck) {
        {
            int lr = 50 + 64 * ck + rrow;
            if (lr <= 525) rowconv(lr);
        }
        __syncthreads();
        #pragma unroll
        for (int g = 0; g < 2; ++g) {
            const int y0 = 64 * ck + g * 32 + (tid >> 5) * 4;
            f2 mu[4];
            #pragma unroll
            for (int j = 0; j < 4; ++j) mu[j] = (f2){0.f, 0.f};
            #pragma unroll
            for (int l = 0; l < 32; ++l) {
                f2 val = r[(((y0 - 14 + l) + RING) & (RING - 1)) * CRP + x];
                #pragma unroll
                for (int j = 0; j < 4; ++j)
                    if (l - j >= 0 && l - j < 29) mu[j] = gw.g[l - j] * val + mu[j];
            }
            #pragma unroll
            for (int j = 0; j < 4; ++j) {
                float p = poly5(mu[j].x);
                if (MODE == 2) {
                    p1 += fabsf(p - mu[j].y * sc_sh);
                } else {
                    p1 += p; p3 += mu[j].y;
                }
            }
        }
        if (ck < 7) __syncthreads();
    }

    if (MODE != 2) { p1 *= wg; p3 *= wg; }
    #pragma unroll
    for (int o = 32; o > 0; o >>= 1) { p1 += __shfl_down(p1, o); p3 += __shfl_down(p3, o); }
    if ((tid & 63) == 0) { red[(tid >> 6) * 2] = p1; red[(tid >> 6) * 2 + 1] = p3; }
    __syncthreads();
    if (tid == 0) {
        float a1 = red[0] + red[2] + red[4] + red[6];
        int stripe = bid & 63;
        if (MODE == 2) {
            atomicAdd(&acc[11 * 64 + stripe], (double)a1);
        } else {
            float a3 = red[1] + red[3] + red[5] + red[7];
            atomicAdd(&acc[(12 + b) * 64 + stripe], (double)a1);
            atomicAdd(&acc[(28 + b) * 64 + stripe], (double)a3);
        }
    }
}

// ---------------- Finalize: combine everything into the scalar ---------------
__global__ void finalize_kernel(const double* __restrict__ acc, float* __restrict__ out)
{
    __shared__ double sums[ACC_SLOTS];
    int t = threadIdx.x;
    if (t < ACC_SLOTS) {
        double s = 0.0;
        for (int i = 0; i < 64; ++i) s += acc[t * 64 + i];
        sums[t] = s;
    }
    __syncthreads();
    if (t == 0) {
        const double w[5] = {0.0448, 0.2856, 0.3001, 0.2363, 0.1333};
        double value = 1.0;
        for (int l = 0; l < 5; ++l) {
            double dim = (double)(512 >> l);
            double cnt = 48.0 * dim * dim;
            double mval = (l < 4) ? (sums[5 + l] / cnt) : (sums[l] / cnt);
            value *= pow(mval, w[l]);
        }
        double n0 = 48.0 * 512.0 * 512.0;
        double l1v = sums[10] / n0;
        double clrv = sums[11] / n0;
        out[0] = (float)(0.4 * (1.0 - value) + 0.4 * l1v + 0.2 * clrv);
    }
}

// ---------------- Launch ------------------------------------------------------
extern "C" void kernel_launch(void* const* d_in, const int* in_sizes, int n_in,
                              void* d_out, int out_size, void* d_ws, size_t ws_size,
                              hipStream_t stream)
{
    (void)in_sizes; (void)n_in; (void)out_size;
    const float* img1 = (const float*)d_in[0];
    const float* img2 = (const float*)d_in[1];
    const float* img3 = (const float*)d_in[2];
    float* out = (float*)d_out;
    double* acc = (double*)d_ws;

    GW11 g11; make_gauss(11, 1.5, g11.g);
    GW7  g7;  make_gauss(7, 1.1, g7.g);
    GW29 g29; make_gauss(29, 29.0 / 6.0, g29.g);

    hipMemsetAsync(d_ws, 0, ACC_BYTES, stream);

    // Interleaved (A,B) float2 pyramid for levels 1..4
    f2* pyr = (f2*)((char*)d_ws + 32768);
    size_t offs[4];
    offs[0] = 0;
    offs[1] = offs[0] + (size_t)48 * 256 * 256;
    offs[2] = offs[1] + (size_t)48 * 128 * 128;
    offs[3] = offs[2] + (size_t)48 * 64 * 64;
    const size_t PYRF2 = offs[3] + (size_t)48 * 32 * 32;

    const size_t poff = 32768 + PYRF2 * sizeof(f2);
    const size_t PBYTES = (size_t)48 * 512 * 512 * sizeof(__half2);
    __half2* pbuf = (__half2*)((char*)d_ws + poff);
    const bool bigws = (ws_size >= poff + PBYTES);

    if (bigws) {
        fused_l0<<<15360, 256, 0, stream>>>(img1, img2, img3, g11, g7, g29,
                                            pbuf, pyr + offs[0], acc);
        // L1 + clr_fin fused (complementary regimes, 1:1 interleave)
        fused_l1<<<6144, 256, 0, stream>>>(pyr + offs[0], pyr + offs[1], pbuf,
                                           g11, g7, acc);
        // Levels 2..4
        const f2* cur = pyr + offs[1];
        int H = 128;
        for (int l = 2; l < 5; ++l) {
            int tilesX = H / 32; int tpp = tilesX * tilesX;
            f2* pooled = (l < 4) ? (pyr + offs[l]) : nullptr;
            int Ho = H / 2;
            ssim_kernel<true><<<48 * tpp, 256, 0, stream>>>(
                nullptr, nullptr, cur, H, tpp, tilesX, g11, g7, acc, l, pooled, Ho);
            cur = pooled; H = Ho;
        }
    } else {
        ssim_kernel<false><<<12288, 256, 0, stream>>>(
            img1, img2, nullptr, 512, 256, 16, g11, g7, acc, 0, pyr + offs[0], 256);
        clr_conv<1><<<768, 256, 0, stream>>>(img1, img3, pbuf, g29, acc);
        const f2* cur = pyr + offs[0];
        int H = 256;
        for (int l = 1; l < 5; ++l) {
            int tilesX = H / 32; int tpp = tilesX * tilesX;
            f2* pooled = (l < 4) ? (pyr + offs[l]) : nullptr;
            int Ho = H / 2;
            ssim_kernel<true><<<48 * tpp, 256, 0, stream>>>(
                nullptr, nullptr, cur, H, tpp, tilesX, g11, g7, acc, l, pooled, Ho);
            cur = pooled; H = Ho;
        }
        clr_conv<2><<<768, 256, 0, stream>>>(img1, img3, pbuf, g29, acc);
    }

    finalize_kernel<<<1, 64, 0, stream>>>(acc, out);
}